// Round 1
// baseline (5985.825 us; speedup 1.0000x reference)
//
#include <hip/hip_runtime.h>
#include <math.h>

#define NN 40000
#define EE 200000
#define DD 32
#define ND (NN * DD)        // 1,280,000
#define HALFND (ND / 2)     // 640,000
#define LNEPS 1e-5f

// RNG variant: 1 = partitionable (counter hi=0, lo=i, take low output word)  [modern JAX default]
//              2 = partitionable, take high output word
//              0 = legacy split-halves counter layout
#define RNG_VARIANT 1

#define SLOT_VLV(it)  (3 * (it))
#define SLOT_VV(it)   (3 * (it) + 1)
#define SLOT_LVLV(it) (3 * (it) + 2)
#define SLOT_ALPHA 15
#define SLOT_VN0   16

__device__ __forceinline__ void threefry2x32(unsigned k0, unsigned k1,
                                             unsigned x0, unsigned x1,
                                             unsigned& o0, unsigned& o1) {
  const unsigned k2 = k0 ^ k1 ^ 0x1BD11BDAu;
  unsigned v0 = x0 + k0, v1 = x1 + k1;
#define TF_ROUND(r) { v0 += v1; v1 = (v1 << (r)) | (v1 >> (32 - (r))); v1 ^= v0; }
  TF_ROUND(13) TF_ROUND(15) TF_ROUND(26) TF_ROUND(6)
  v0 += k1; v1 += k2 + 1u;
  TF_ROUND(17) TF_ROUND(29) TF_ROUND(16) TF_ROUND(24)
  v0 += k2; v1 += k0 + 2u;
  TF_ROUND(13) TF_ROUND(15) TF_ROUND(26) TF_ROUND(6)
  v0 += k0; v1 += k1 + 3u;
  TF_ROUND(17) TF_ROUND(29) TF_ROUND(16) TF_ROUND(24)
  v0 += k1; v1 += k2 + 4u;
  TF_ROUND(13) TF_ROUND(15) TF_ROUND(26) TF_ROUND(6)
  v0 += k2; v1 += k0 + 5u;
#undef TF_ROUND
  o0 = v0; o1 = v1;
}

__device__ __forceinline__ float wave64_sum(float x) {
  for (int o = 32; o > 0; o >>= 1) x += __shfl_xor(x, o, 64);
  return x;
}
__device__ __forceinline__ float g32_sum(float x) {
  for (int o = 16; o > 0; o >>= 1) x += __shfl_xor(x, o, 32);
  return x;
}

__global__ void k_deg(const int* __restrict__ ei, float* __restrict__ deg) {
  int e = blockIdx.x * 256 + threadIdx.x;
  if (e < EE) {
    atomicAdd(deg + ei[e], 1.0f);
    atomicAdd(deg + ei[EE + e], 1.0f);
  }
}

__global__ void k_genv(float* __restrict__ v, float* __restrict__ scal) {
  int i = blockIdx.x * 256 + threadIdx.x;  // exact ND
  unsigned o0, o1, bits;
#if RNG_VARIANT == 1
  threefry2x32(0u, 42u, 0u, (unsigned)i, o0, o1); bits = o1;
#elif RNG_VARIANT == 2
  threefry2x32(0u, 42u, 0u, (unsigned)i, o0, o1); bits = o0;
#else
  {
    unsigned j = (i < HALFND) ? (unsigned)i : (unsigned)(i - HALFND);
    threefry2x32(0u, 42u, j, j + (unsigned)HALFND, o0, o1);
    bits = (i < HALFND) ? o0 : o1;
  }
#endif
  float f = __uint_as_float((bits >> 9) | 0x3f800000u) - 1.0f;  // [0,1)
  const float lo = -0.99999994f;                                 // nextafter(-1,0) f32
  float u = fmaxf(lo, f * 2.0f + lo);                            // (hi-lo) rounds to 2.0f
  float val = 1.41421354f * erfinvf(u);                          // f32(sqrt(2))
  v[i] = val;
  float s = wave64_sum(val * val);
  if ((threadIdx.x & 63) == 0) atomicAdd(scal + SLOT_VN0, s);
}

__global__ void k_norm0(float* __restrict__ v, const float* __restrict__ scal) {
  int i = blockIdx.x * 256 + threadIdx.x;
  v[i] = v[i] / sqrtf(scal[SLOT_VN0]);
}

__global__ __launch_bounds__(256) void k_matvec(const float* __restrict__ x,
                                                const float* __restrict__ Q,
                                                const int* __restrict__ ei,
                                                float* __restrict__ off) {
  const int slot = threadIdx.x >> 5;
  const int lane = threadIdx.x & 31;
  const int e = blockIdx.x * 8 + slot;
  if (e >= EE) return;
  const int row = ei[e];
  const int col = ei[EE + e];
  const float4* __restrict__ x4 = (const float4*)(x + (size_t)col * DD);
  float4 xr[8];
#pragma unroll
  for (int k = 0; k < 8; ++k) xr[k] = x4[k];
  const float4* __restrict__ q4 =
      (const float4*)(Q + (size_t)e * (DD * DD) + (size_t)lane * DD);
  float acc = 0.0f;
#pragma unroll
  for (int k = 0; k < 8; ++k) {
    float4 q = q4[k];
    acc = fmaf(q.x, xr[k].x, acc);
    acc = fmaf(q.y, xr[k].y, acc);
    acc = fmaf(q.z, xr[k].z, acc);
    acc = fmaf(q.w, xr[k].w, acc);
  }
  atomicAdd(off + (size_t)row * DD + lane, acc);
}

__global__ void k_finish(const float* __restrict__ v, const float* __restrict__ off,
                         const float* __restrict__ deg, float* __restrict__ Lv,
                         float* __restrict__ scal, int it) {
  int i = blockIdx.x * 256 + threadIdx.x;
  float vi = v[i];
  float lv = deg[i >> 5] * vi - off[i];
  Lv[i] = lv;
  float a = wave64_sum(vi * lv);
  float b = wave64_sum(vi * vi);
  float c = wave64_sum(lv * lv);
  if ((threadIdx.x & 63) == 0) {
    atomicAdd(scal + SLOT_VLV(it), a);
    atomicAdd(scal + SLOT_VV(it), b);
    atomicAdd(scal + SLOT_LVLV(it), c);
  }
}

__global__ void k_update(float* __restrict__ v, const float* __restrict__ Lv,
                         float* __restrict__ scal, int it) {
  int i = blockIdx.x * 256 + threadIdx.x;
  float inv = 1.0f / (sqrtf(scal[SLOT_LVLV(it)]) + 1e-8f);
  v[i] = Lv[i] * inv;
  if (it == 4 && i == 0) {
    float lam = scal[SLOT_VLV(4)] / (scal[SLOT_VV(4)] + 1e-8f);
    lam = fmaxf(lam, 1.0f);
    scal[SLOT_ALPHA] = 2.0f / (lam + 1e-8f);
  }
}

__global__ void k_cheb(const float* __restrict__ x, const float* __restrict__ xprev,
                       const float* __restrict__ off, const float* __restrict__ deg,
                       const float* __restrict__ scal, float* __restrict__ Tout,
                       int first) {
  int i = blockIdx.x * 256 + threadIdx.x;
  float alpha = scal[SLOT_ALPHA];
  float xi = x[i];
  float lt = alpha * (deg[i >> 5] * xi - off[i]) - xi;
  Tout[i] = first ? lt : (2.0f * lt - xprev[i]);
}

__global__ __launch_bounds__(256) void k_fuse(
    const float* __restrict__ h,
    const float* __restrict__ T1, const float* __restrict__ T2,
    const float* __restrict__ T3, const float* __restrict__ T4,
    const float* __restrict__ coeffs,
    const float* __restrict__ projW, const float* __restrict__ projb,
    const float* __restrict__ projg, const float* __restrict__ projbeta,
    const float* __restrict__ fusW1, const float* __restrict__ fusb1,
    const float* __restrict__ fusg, const float* __restrict__ fusbeta,
    const float* __restrict__ fusW2, const float* __restrict__ fusb2,
    float* __restrict__ out) {
  __shared__ float s_res[8][3][DD];
  __shared__ float s_p[8][3 * DD];
  __shared__ float s_s[8][DD];
  const int slot = threadIdx.x >> 5;
  const int lane = threadIdx.x & 31;
  const int n = blockIdx.x * 8 + slot;  // 5000 blocks exact

  float w[3][5];
#pragma unroll
  for (int b = 0; b < 3; ++b) {
    float m = -1e30f;
#pragma unroll
    for (int k = 0; k < 5; ++k) m = fmaxf(m, coeffs[b * 5 + k]);
    float s = 0.0f;
#pragma unroll
    for (int k = 0; k < 5; ++k) { w[b][k] = expf(coeffs[b * 5 + k] - m); s += w[b][k]; }
#pragma unroll
    for (int k = 0; k < 5; ++k) w[b][k] /= s;
  }

  const int idx = n * DD + lane;
  float hd = h[idx], t1 = T1[idx], t2 = T2[idx], t3 = T3[idx], t4 = T4[idx];
#pragma unroll
  for (int b = 0; b < 3; ++b)
    s_res[slot][b][lane] =
        w[b][0] * hd + w[b][1] * t1 + w[b][2] * t2 + w[b][3] * t3 + w[b][4] * t4;
  __syncthreads();

#pragma unroll
  for (int b = 0; b < 3; ++b) {
    float y = projb[b * DD + lane];
#pragma unroll
    for (int j = 0; j < DD; ++j)
      y = fmaf(s_res[slot][b][j], projW[(b * DD + j) * DD + lane], y);
    float mu = g32_sum(y) * (1.0f / DD);
    float d = y - mu;
    float var = g32_sum(d * d) * (1.0f / DD);
    float z = d * rsqrtf(var + LNEPS) * projg[b * DD + lane] + projbeta[b * DD + lane];
    float pb = z / (1.0f + expf(-z));  // silu
    s_p[slot][b * DD + lane] = pb;
  }
  __syncthreads();

  float y = fusb1[lane];
#pragma unroll
  for (int j = 0; j < 3 * DD; ++j)
    y = fmaf(s_p[slot][j], fusW1[j * DD + lane], y);
  float mu = g32_sum(y) * (1.0f / DD);
  float d = y - mu;
  float var = g32_sum(d * d) * (1.0f / DD);
  float z = d * rsqrtf(var + LNEPS) * fusg[lane] + fusbeta[lane];
  float sv = z / (1.0f + expf(-z));
  s_s[slot][lane] = sv;
  __syncthreads();

  float o = fusb2[lane];
#pragma unroll
  for (int j = 0; j < DD; ++j)
    o = fmaf(s_s[slot][j], fusW2[j * DD + lane], o);
  out[idx] = hd + o;
}

extern "C" void kernel_launch(void* const* d_in, const int* in_sizes, int n_in,
                              void* d_out, int out_size, void* d_ws, size_t ws_size,
                              hipStream_t stream) {
  (void)in_sizes; (void)n_in; (void)out_size; (void)ws_size;
  const float* h        = (const float*)d_in[0];
  const float* Q        = (const float*)d_in[1];
  const int*   ei       = (const int*)d_in[2];
  const float* coeffs   = (const float*)d_in[3];
  const float* projW    = (const float*)d_in[4];
  const float* projb    = (const float*)d_in[5];
  const float* projg    = (const float*)d_in[6];
  const float* projbeta = (const float*)d_in[7];
  const float* fusW1    = (const float*)d_in[8];
  const float* fusb1    = (const float*)d_in[9];
  const float* fusg     = (const float*)d_in[10];
  const float* fusbeta  = (const float*)d_in[11];
  const float* fusW2    = (const float*)d_in[12];
  const float* fusb2    = (const float*)d_in[13];
  float* out = (float*)d_out;

  float* off  = (float*)d_ws;     // [ND]
  float* v    = off + ND;         // [ND]
  float* Lv   = v + ND;           // [ND]
  float* T1   = Lv + ND;          // [ND]
  float* T2   = T1 + ND;          // [ND]
  float* T3   = T2 + ND;          // [ND]
  float* T4   = T3 + ND;          // [ND]
  float* deg  = T4 + ND;          // [NN]
  float* scal = deg + NN;         // [64]

  hipMemsetAsync(deg, 0, (NN + 64) * sizeof(float), stream);

  k_deg<<<(EE + 255) / 256, 256, 0, stream>>>(ei, deg);
  k_genv<<<ND / 256, 256, 0, stream>>>(v, scal);
  k_norm0<<<ND / 256, 256, 0, stream>>>(v, scal);

  for (int it = 0; it < 5; ++it) {
    hipMemsetAsync(off, 0, ND * sizeof(float), stream);
    k_matvec<<<EE / 8, 256, 0, stream>>>(v, Q, ei, off);
    k_finish<<<ND / 256, 256, 0, stream>>>(v, off, deg, Lv, scal, it);
    k_update<<<ND / 256, 256, 0, stream>>>(v, Lv, scal, it);
  }

  // Chebyshev T1..T4 (T0 = h)
  const float* xin[4]   = {h, T1, T2, T3};
  const float* prevs[4] = {h, h, T1, T2};  // prevs[0] unused
  float* touts[4]       = {T1, T2, T3, T4};
  for (int k = 0; k < 4; ++k) {
    hipMemsetAsync(off, 0, ND * sizeof(float), stream);
    k_matvec<<<EE / 8, 256, 0, stream>>>(xin[k], Q, ei, off);
    k_cheb<<<ND / 256, 256, 0, stream>>>(xin[k], prevs[k], off, deg, scal,
                                         touts[k], k == 0 ? 1 : 0);
  }

  k_fuse<<<NN / 8, 256, 0, stream>>>(h, T1, T2, T3, T4, coeffs,
                                     projW, projb, projg, projbeta,
                                     fusW1, fusb1, fusg, fusbeta,
                                     fusW2, fusb2, out);
}

// Round 2
// 2048.598 us; speedup vs baseline: 2.9219x; 2.9219x over previous
//
#include <hip/hip_runtime.h>
#include <math.h>

#define NN 40000
#define EE 200000
#define DD 32
#define ND (NN * DD)        // 1,280,000
#define LNEPS 1e-5f

// scal slots — keep atomically-updated slots on separate 128B cache lines
#define SLOT_S1    0    // u4 . u5
#define SLOT_S2    32   // u4 . u4
#define SLOT_ALPHA 48   // 2 / (lam + eps)

__device__ __forceinline__ void threefry2x32(unsigned k0, unsigned k1,
                                             unsigned x0, unsigned x1,
                                             unsigned& o0, unsigned& o1) {
  const unsigned k2 = k0 ^ k1 ^ 0x1BD11BDAu;
  unsigned v0 = x0 + k0, v1 = x1 + k1;
#define TF_ROUND(r) { v0 += v1; v1 = (v1 << (r)) | (v1 >> (32 - (r))); v1 ^= v0; }
  TF_ROUND(13) TF_ROUND(15) TF_ROUND(26) TF_ROUND(6)
  v0 += k1; v1 += k2 + 1u;
  TF_ROUND(17) TF_ROUND(29) TF_ROUND(16) TF_ROUND(24)
  v0 += k2; v1 += k0 + 2u;
  TF_ROUND(13) TF_ROUND(15) TF_ROUND(26) TF_ROUND(6)
  v0 += k0; v1 += k1 + 3u;
  TF_ROUND(17) TF_ROUND(29) TF_ROUND(16) TF_ROUND(24)
  v0 += k1; v1 += k2 + 4u;
  TF_ROUND(13) TF_ROUND(15) TF_ROUND(26) TF_ROUND(6)
  v0 += k2; v1 += k0 + 5u;
#undef TF_ROUND
  o0 = v0; o1 = v1;
}

__device__ __forceinline__ float wave64_sum(float x) {
  for (int o = 32; o > 0; o >>= 1) x += __shfl_xor(x, o, 64);
  return x;
}
__device__ __forceinline__ float g32_sum(float x) {
  for (int o = 16; o > 0; o >>= 1) x += __shfl_xor(x, o, 32);
  return x;
}

__global__ void k_deg(const int* __restrict__ ei, float* __restrict__ deg) {
  int e = blockIdx.x * 256 + threadIdx.x;
  if (e < EE) {
    atomicAdd(deg + ei[e], 1.0f);
    atomicAdd(deg + ei[EE + e], 1.0f);
  }
}

// v0 = N(0,1) via exact JAX threefry pipeline; normalization deferred (scale-free).
__global__ void k_genv(float* __restrict__ v) {
  int i = blockIdx.x * 256 + threadIdx.x;  // exact ND
  unsigned o0, o1;
  threefry2x32(0u, 42u, 0u, (unsigned)i, o0, o1);
  unsigned bits = o1;
  float f = __uint_as_float((bits >> 9) | 0x3f800000u) - 1.0f;  // [0,1)
  const float lo = -0.99999994f;                                 // nextafter(-1,0)
  float u = fmaxf(lo, f * 2.0f + lo);
  v[i] = 1.41421354f * erfinvf(u);
}

// out = diag part (+ Chebyshev affine terms); matvec then atomically subtracts Q-part.
// mode 0: out = deg*x                      (power iteration: out -> L x)
// mode 1: out = alpha*deg*x - x            (T1 = Ltilde h)
// mode 2: out = 2*alpha*deg*x - 2x - xprev (T_next)
__global__ void k_pre(const float* __restrict__ x, const float* __restrict__ xprev,
                      const float* __restrict__ deg, const float* __restrict__ scal,
                      float* __restrict__ out, int mode) {
  int i = blockIdx.x * 256 + threadIdx.x;
  float d = deg[i >> 5];
  float xi = x[i];
  if (mode == 0)       out[i] = d * xi;
  else if (mode == 1)  out[i] = scal[SLOT_ALPHA] * d * xi - xi;
  else                 out[i] = 2.0f * scal[SLOT_ALPHA] * d * xi - 2.0f * xi - xprev[i];
}

__global__ __launch_bounds__(256) void k_matvec(const float* __restrict__ x,
                                                const float* __restrict__ Q,
                                                const int* __restrict__ ei,
                                                float* __restrict__ out,
                                                const float* __restrict__ scal,
                                                int use_alpha, float smul) {
  const int slot = threadIdx.x >> 5;
  const int lane = threadIdx.x & 31;
  const int e = blockIdx.x * 8 + slot;  // EE % 8 == 0
  const float factor = use_alpha ? scal[SLOT_ALPHA] * smul : smul;
  const int row = ei[e];
  const int col = ei[EE + e];
  const float4* __restrict__ x4 = (const float4*)(x + (size_t)col * DD);
  float4 xr[8];
#pragma unroll
  for (int k = 0; k < 8; ++k) xr[k] = x4[k];
  const float4* __restrict__ q4 =
      (const float4*)(Q + (size_t)e * (DD * DD) + (size_t)lane * DD);
  float acc = 0.0f;
#pragma unroll
  for (int k = 0; k < 8; ++k) {
    float4 q = q4[k];
    acc = fmaf(q.x, xr[k].x, acc);
    acc = fmaf(q.y, xr[k].y, acc);
    acc = fmaf(q.z, xr[k].z, acc);
    acc = fmaf(q.w, xr[k].w, acc);
  }
  atomicAdd(out + (size_t)row * DD + lane, -factor * acc);
}

#define DOT_BLOCKS 640
__global__ void k_dots(const float* __restrict__ u4, const float* __restrict__ u5,
                       float* __restrict__ scal) {
  float s1 = 0.0f, s2 = 0.0f;
  for (int i = blockIdx.x * 256 + threadIdx.x; i < ND; i += DOT_BLOCKS * 256) {
    float a = u4[i], b = u5[i];
    s1 = fmaf(a, b, s1);
    s2 = fmaf(a, a, s2);
  }
  s1 = wave64_sum(s1);
  s2 = wave64_sum(s2);
  __shared__ float ls1[4], ls2[4];
  int w = threadIdx.x >> 6;
  if ((threadIdx.x & 63) == 0) { ls1[w] = s1; ls2[w] = s2; }
  __syncthreads();
  if (threadIdx.x == 0) {
    atomicAdd(scal + SLOT_S1, ls1[0] + ls1[1] + ls1[2] + ls1[3]);
    atomicAdd(scal + SLOT_S2, ls2[0] + ls2[1] + ls2[2] + ls2[3]);
  }
}

__global__ void k_alpha(float* __restrict__ scal) {
  // v = u4/||u4||  =>  v.v = 1 exactly; lam = (v.Lv)/((v.v)+1e-8)
  float lam = scal[SLOT_S1] / scal[SLOT_S2] / (1.0f + 1e-8f);
  lam = fmaxf(lam, 1.0f);
  scal[SLOT_ALPHA] = 2.0f / (lam + 1e-8f);
}

__global__ __launch_bounds__(256) void k_fuse(
    const float* __restrict__ h,
    const float* __restrict__ T1, const float* __restrict__ T2,
    const float* __restrict__ T3, const float* __restrict__ T4,
    const float* __restrict__ coeffs,
    const float* __restrict__ projW, const float* __restrict__ projb,
    const float* __restrict__ projg, const float* __restrict__ projbeta,
    const float* __restrict__ fusW1, const float* __restrict__ fusb1,
    const float* __restrict__ fusg, const float* __restrict__ fusbeta,
    const float* __restrict__ fusW2, const float* __restrict__ fusb2,
    float* __restrict__ out) {
  __shared__ float s_res[8][3][DD];
  __shared__ float s_p[8][3 * DD];
  __shared__ float s_s[8][DD];
  const int slot = threadIdx.x >> 5;
  const int lane = threadIdx.x & 31;
  const int n = blockIdx.x * 8 + slot;  // 5000 blocks exact

  float w[3][5];
#pragma unroll
  for (int b = 0; b < 3; ++b) {
    float m = -1e30f;
#pragma unroll
    for (int k = 0; k < 5; ++k) m = fmaxf(m, coeffs[b * 5 + k]);
    float s = 0.0f;
#pragma unroll
    for (int k = 0; k < 5; ++k) { w[b][k] = expf(coeffs[b * 5 + k] - m); s += w[b][k]; }
#pragma unroll
    for (int k = 0; k < 5; ++k) w[b][k] /= s;
  }

  const int idx = n * DD + lane;
  float hd = h[idx], t1 = T1[idx], t2 = T2[idx], t3 = T3[idx], t4 = T4[idx];
#pragma unroll
  for (int b = 0; b < 3; ++b)
    s_res[slot][b][lane] =
        w[b][0] * hd + w[b][1] * t1 + w[b][2] * t2 + w[b][3] * t3 + w[b][4] * t4;
  __syncthreads();

#pragma unroll
  for (int b = 0; b < 3; ++b) {
    float y = projb[b * DD + lane];
#pragma unroll
    for (int j = 0; j < DD; ++j)
      y = fmaf(s_res[slot][b][j], projW[(b * DD + j) * DD + lane], y);
    float mu = g32_sum(y) * (1.0f / DD);
    float d = y - mu;
    float var = g32_sum(d * d) * (1.0f / DD);
    float z = d * rsqrtf(var + LNEPS) * projg[b * DD + lane] + projbeta[b * DD + lane];
    float pb = z / (1.0f + expf(-z));  // silu
    s_p[slot][b * DD + lane] = pb;
  }
  __syncthreads();

  float y = fusb1[lane];
#pragma unroll
  for (int j = 0; j < 3 * DD; ++j)
    y = fmaf(s_p[slot][j], fusW1[j * DD + lane], y);
  float mu = g32_sum(y) * (1.0f / DD);
  float d = y - mu;
  float var = g32_sum(d * d) * (1.0f / DD);
  float z = d * rsqrtf(var + LNEPS) * fusg[lane] + fusbeta[lane];
  float sv = z / (1.0f + expf(-z));
  s_s[slot][lane] = sv;
  __syncthreads();

  float o = fusb2[lane];
#pragma unroll
  for (int j = 0; j < DD; ++j)
    o = fmaf(s_s[slot][j], fusW2[j * DD + lane], o);
  out[idx] = hd + o;
}

extern "C" void kernel_launch(void* const* d_in, const int* in_sizes, int n_in,
                              void* d_out, int out_size, void* d_ws, size_t ws_size,
                              hipStream_t stream) {
  (void)in_sizes; (void)n_in; (void)out_size; (void)ws_size;
  const float* h        = (const float*)d_in[0];
  const float* Q        = (const float*)d_in[1];
  const int*   ei       = (const int*)d_in[2];
  const float* coeffs   = (const float*)d_in[3];
  const float* projW    = (const float*)d_in[4];
  const float* projb    = (const float*)d_in[5];
  const float* projg    = (const float*)d_in[6];
  const float* projbeta = (const float*)d_in[7];
  const float* fusW1    = (const float*)d_in[8];
  const float* fusb1    = (const float*)d_in[9];
  const float* fusg     = (const float*)d_in[10];
  const float* fusbeta  = (const float*)d_in[11];
  const float* fusW2    = (const float*)d_in[12];
  const float* fusb2    = (const float*)d_in[13];
  float* out = (float*)d_out;

  float* uA   = (float*)d_ws;     // [ND]
  float* uB   = uA + ND;          // [ND]
  float* T1   = uB + ND;          // [ND]
  float* T2   = T1 + ND;          // [ND]
  float* T3   = T2 + ND;          // [ND]
  float* T4   = T3 + ND;          // [ND]
  float* deg  = T4 + ND;          // [NN]
  float* scal = deg + NN;         // [64]

  hipMemsetAsync(deg, 0, (NN + 64) * sizeof(float), stream);

  k_deg<<<(EE + 255) / 256, 256, 0, stream>>>(ei, deg);
  k_genv<<<ND / 256, 256, 0, stream>>>(uA);

  // power iteration, unnormalized: u_{k+1} = L u_k
  float* cur = uA;
  float* nxt = uB;
  for (int it = 0; it < 5; ++it) {
    k_pre<<<ND / 256, 256, 0, stream>>>(cur, nullptr, deg, scal, nxt, 0);
    k_matvec<<<EE / 8, 256, 0, stream>>>(cur, Q, ei, nxt, scal, 0, 1.0f);
    float* t = cur; cur = nxt; nxt = t;
  }
  // cur = u5, nxt = u4
  k_dots<<<DOT_BLOCKS, 256, 0, stream>>>(nxt, cur, scal);
  k_alpha<<<1, 1, 0, stream>>>(scal);

  // Chebyshev: T1 = alpha*L h - h ; T_next = 2*(alpha*L x - x) - xprev
  k_pre<<<ND / 256, 256, 0, stream>>>(h, nullptr, deg, scal, T1, 1);
  k_matvec<<<EE / 8, 256, 0, stream>>>(h, Q, ei, T1, scal, 1, 1.0f);

  const float* xin[3]   = {T1, T2, T3};
  const float* prevs[3] = {h, T1, T2};
  float* touts[3]       = {T2, T3, T4};
  for (int k = 0; k < 3; ++k) {
    k_pre<<<ND / 256, 256, 0, stream>>>(xin[k], prevs[k], deg, scal, touts[k], 2);
    k_matvec<<<EE / 8, 256, 0, stream>>>(xin[k], Q, ei, touts[k], scal, 1, 2.0f);
  }

  k_fuse<<<NN / 8, 256, 0, stream>>>(h, T1, T2, T3, T4, coeffs,
                                     projW, projb, projg, projbeta,
                                     fusW1, fusb1, fusg, fusbeta,
                                     fusW2, fusb2, out);
}

// Round 3
// 1111.583 us; speedup vs baseline: 5.3850x; 1.8430x over previous
//
#include <hip/hip_runtime.h>
#include <hip/hip_fp16.h>
#include <math.h>

#define NN 40000
#define EE 200000
#define DD 32
#define ND (NN * DD)        // 1,280,000
#define LNEPS 1e-5f

// scal slots — separate cache lines for atomically-updated slots
#define SLOT_S1    0    // u4 . u5
#define SLOT_S2    32   // u4 . u4
#define SLOT_ALPHA 48   // 2 / (lam + eps)

__device__ __forceinline__ void threefry2x32(unsigned k0, unsigned k1,
                                             unsigned x0, unsigned x1,
                                             unsigned& o0, unsigned& o1) {
  const unsigned k2 = k0 ^ k1 ^ 0x1BD11BDAu;
  unsigned v0 = x0 + k0, v1 = x1 + k1;
#define TF_ROUND(r) { v0 += v1; v1 = (v1 << (r)) | (v1 >> (32 - (r))); v1 ^= v0; }
  TF_ROUND(13) TF_ROUND(15) TF_ROUND(26) TF_ROUND(6)
  v0 += k1; v1 += k2 + 1u;
  TF_ROUND(17) TF_ROUND(29) TF_ROUND(16) TF_ROUND(24)
  v0 += k2; v1 += k0 + 2u;
  TF_ROUND(13) TF_ROUND(15) TF_ROUND(26) TF_ROUND(6)
  v0 += k0; v1 += k1 + 3u;
  TF_ROUND(17) TF_ROUND(29) TF_ROUND(16) TF_ROUND(24)
  v0 += k1; v1 += k2 + 4u;
  TF_ROUND(13) TF_ROUND(15) TF_ROUND(26) TF_ROUND(6)
  v0 += k2; v1 += k0 + 5u;
#undef TF_ROUND
  o0 = v0; o1 = v1;
}

__device__ __forceinline__ float wave64_sum(float x) {
  for (int o = 32; o > 0; o >>= 1) x += __shfl_xor(x, o, 64);
  return x;
}
__device__ __forceinline__ float g32_sum(float x) {
  for (int o = 16; o > 0; o >>= 1) x += __shfl_xor(x, o, 32);
  return x;
}

__global__ void k_deg(const int* __restrict__ ei, float* __restrict__ deg) {
  int e = blockIdx.x * 256 + threadIdx.x;
  if (e < EE) {
    atomicAdd(deg + ei[e], 1.0f);
    atomicAdd(deg + ei[EE + e], 1.0f);
  }
}

// v0 = N(0,1) via exact JAX threefry pipeline; normalization deferred (scale-free).
__global__ void k_genv(float* __restrict__ v) {
  int i = blockIdx.x * 256 + threadIdx.x;  // exact ND
  unsigned o0, o1;
  threefry2x32(0u, 42u, 0u, (unsigned)i, o0, o1);
  unsigned bits = o1;
  float f = __uint_as_float((bits >> 9) | 0x3f800000u) - 1.0f;  // [0,1)
  const float lo = -0.99999994f;                                 // nextafter(-1,0)
  float u = fmaxf(lo, f * 2.0f + lo);
  v[i] = 1.41421354f * erfinvf(u);
}

// out = diag part (+ Chebyshev affine terms); matvec then atomically subtracts Q-part.
// mode 0: out = deg*x                      (power iteration: out -> L x)
// mode 1: out = alpha*deg*x - x            (T1 = Ltilde h)
// mode 2: out = 2*alpha*deg*x - 2x - xprev (T_next)
__global__ void k_pre(const float* __restrict__ x, const float* __restrict__ xprev,
                      const float* __restrict__ deg, const float* __restrict__ scal,
                      float* __restrict__ out, int mode) {
  int i = blockIdx.x * 256 + threadIdx.x;
  float d = deg[i >> 5];
  float xi = x[i];
  if (mode == 0)       out[i] = d * xi;
  else if (mode == 1)  out[i] = scal[SLOT_ALPHA] * d * xi - xi;
  else                 out[i] = 2.0f * scal[SLOT_ALPHA] * d * xi - 2.0f * xi - xprev[i];
}

// f32 sweep (power iter #1), fused Q -> fp16 conversion for later sweeps.
__global__ __launch_bounds__(256) void k_matvec_cvt(const float* __restrict__ x,
                                                    const float* __restrict__ Q,
                                                    const int* __restrict__ ei,
                                                    float* __restrict__ out,
                                                    __half* __restrict__ Qh) {
  const int slot = threadIdx.x >> 5;
  const int lane = threadIdx.x & 31;
  const int e = blockIdx.x * 8 + slot;  // EE % 8 == 0
  const int row = ei[e];
  const int col = ei[EE + e];
  const float4* __restrict__ x4 = (const float4*)(x + (size_t)col * DD);
  float4 xr[8];
#pragma unroll
  for (int k = 0; k < 8; ++k) xr[k] = x4[k];
  const float4* __restrict__ q4 =
      (const float4*)(Q + (size_t)e * (DD * DD) + (size_t)lane * DD);
  float4 qf[8];
#pragma unroll
  for (int k = 0; k < 8; ++k) qf[k] = q4[k];
  float acc = 0.0f;
#pragma unroll
  for (int k = 0; k < 8; ++k) {
    acc = fmaf(qf[k].x, xr[k].x, acc);
    acc = fmaf(qf[k].y, xr[k].y, acc);
    acc = fmaf(qf[k].z, xr[k].z, acc);
    acc = fmaf(qf[k].w, xr[k].w, acc);
  }
  uint4* __restrict__ qs = (uint4*)(Qh + (size_t)e * (DD * DD) + (size_t)lane * DD);
#pragma unroll
  for (int k = 0; k < 4; ++k) {
    __half2 h0 = __floats2half2_rn(qf[2 * k].x,     qf[2 * k].y);
    __half2 h1 = __floats2half2_rn(qf[2 * k].z,     qf[2 * k].w);
    __half2 h2 = __floats2half2_rn(qf[2 * k + 1].x, qf[2 * k + 1].y);
    __half2 h3 = __floats2half2_rn(qf[2 * k + 1].z, qf[2 * k + 1].w);
    uint4 u;
    u.x = *(unsigned*)&h0; u.y = *(unsigned*)&h1;
    u.z = *(unsigned*)&h2; u.w = *(unsigned*)&h3;
    qs[k] = u;
  }
  atomicAdd(out + (size_t)row * DD + lane, -acc);
}

// fp16-Q sweep; f32 vectors and accumulation.
__global__ __launch_bounds__(256) void k_matvec_h(const float* __restrict__ x,
                                                  const __half* __restrict__ Qh,
                                                  const int* __restrict__ ei,
                                                  float* __restrict__ out,
                                                  const float* __restrict__ scal,
                                                  int use_alpha, float smul) {
  const int slot = threadIdx.x >> 5;
  const int lane = threadIdx.x & 31;
  const int e = blockIdx.x * 8 + slot;
  const float factor = use_alpha ? scal[SLOT_ALPHA] * smul : smul;
  const int row = ei[e];
  const int col = ei[EE + e];
  const float4* __restrict__ x4 = (const float4*)(x + (size_t)col * DD);
  float4 xr[8];
#pragma unroll
  for (int k = 0; k < 8; ++k) xr[k] = x4[k];
  const uint4* __restrict__ q4 =
      (const uint4*)(Qh + (size_t)e * (DD * DD) + (size_t)lane * DD);
  float acc = 0.0f;
#pragma unroll
  for (int k = 0; k < 4; ++k) {
    uint4 u = q4[k];
    float2 f0 = __half22float2(*(__half2*)&u.x);
    float2 f1 = __half22float2(*(__half2*)&u.y);
    float2 f2 = __half22float2(*(__half2*)&u.z);
    float2 f3 = __half22float2(*(__half2*)&u.w);
    float4 xa = xr[2 * k], xb = xr[2 * k + 1];
    acc = fmaf(f0.x, xa.x, acc); acc = fmaf(f0.y, xa.y, acc);
    acc = fmaf(f1.x, xa.z, acc); acc = fmaf(f1.y, xa.w, acc);
    acc = fmaf(f2.x, xb.x, acc); acc = fmaf(f2.y, xb.y, acc);
    acc = fmaf(f3.x, xb.z, acc); acc = fmaf(f3.y, xb.w, acc);
  }
  atomicAdd(out + (size_t)row * DD + lane, -factor * acc);
}

// f32 fallback (only used if ws_size is too small for the fp16 Q copy)
__global__ __launch_bounds__(256) void k_matvec(const float* __restrict__ x,
                                                const float* __restrict__ Q,
                                                const int* __restrict__ ei,
                                                float* __restrict__ out,
                                                const float* __restrict__ scal,
                                                int use_alpha, float smul) {
  const int slot = threadIdx.x >> 5;
  const int lane = threadIdx.x & 31;
  const int e = blockIdx.x * 8 + slot;
  const float factor = use_alpha ? scal[SLOT_ALPHA] * smul : smul;
  const int row = ei[e];
  const int col = ei[EE + e];
  const float4* __restrict__ x4 = (const float4*)(x + (size_t)col * DD);
  float4 xr[8];
#pragma unroll
  for (int k = 0; k < 8; ++k) xr[k] = x4[k];
  const float4* __restrict__ q4 =
      (const float4*)(Q + (size_t)e * (DD * DD) + (size_t)lane * DD);
  float acc = 0.0f;
#pragma unroll
  for (int k = 0; k < 8; ++k) {
    float4 q = q4[k];
    acc = fmaf(q.x, xr[k].x, acc);
    acc = fmaf(q.y, xr[k].y, acc);
    acc = fmaf(q.z, xr[k].z, acc);
    acc = fmaf(q.w, xr[k].w, acc);
  }
  atomicAdd(out + (size_t)row * DD + lane, -factor * acc);
}

#define DOT_BLOCKS 640
__global__ void k_dots(const float* __restrict__ u4, const float* __restrict__ u5,
                       float* __restrict__ scal) {
  float s1 = 0.0f, s2 = 0.0f;
  for (int i = blockIdx.x * 256 + threadIdx.x; i < ND; i += DOT_BLOCKS * 256) {
    float a = u4[i], b = u5[i];
    s1 = fmaf(a, b, s1);
    s2 = fmaf(a, a, s2);
  }
  s1 = wave64_sum(s1);
  s2 = wave64_sum(s2);
  __shared__ float ls1[4], ls2[4];
  int w = threadIdx.x >> 6;
  if ((threadIdx.x & 63) == 0) { ls1[w] = s1; ls2[w] = s2; }
  __syncthreads();
  if (threadIdx.x == 0) {
    atomicAdd(scal + SLOT_S1, ls1[0] + ls1[1] + ls1[2] + ls1[3]);
    atomicAdd(scal + SLOT_S2, ls2[0] + ls2[1] + ls2[2] + ls2[3]);
  }
}

__global__ void k_alpha(float* __restrict__ scal) {
  float lam = scal[SLOT_S1] / scal[SLOT_S2] / (1.0f + 1e-8f);
  lam = fmaxf(lam, 1.0f);
  scal[SLOT_ALPHA] = 2.0f / (lam + 1e-8f);
}

__global__ __launch_bounds__(256) void k_fuse(
    const float* __restrict__ h,
    const float* __restrict__ T1, const float* __restrict__ T2,
    const float* __restrict__ T3, const float* __restrict__ T4,
    const float* __restrict__ coeffs,
    const float* __restrict__ projW, const float* __restrict__ projb,
    const float* __restrict__ projg, const float* __restrict__ projbeta,
    const float* __restrict__ fusW1, const float* __restrict__ fusb1,
    const float* __restrict__ fusg, const float* __restrict__ fusbeta,
    const float* __restrict__ fusW2, const float* __restrict__ fusb2,
    float* __restrict__ out) {
  __shared__ float s_res[8][3][DD];
  __shared__ float s_p[8][3 * DD];
  __shared__ float s_s[8][DD];
  const int slot = threadIdx.x >> 5;
  const int lane = threadIdx.x & 31;
  const int n = blockIdx.x * 8 + slot;  // 5000 blocks exact

  float w[3][5];
#pragma unroll
  for (int b = 0; b < 3; ++b) {
    float m = -1e30f;
#pragma unroll
    for (int k = 0; k < 5; ++k) m = fmaxf(m, coeffs[b * 5 + k]);
    float s = 0.0f;
#pragma unroll
    for (int k = 0; k < 5; ++k) { w[b][k] = expf(coeffs[b * 5 + k] - m); s += w[b][k]; }
#pragma unroll
    for (int k = 0; k < 5; ++k) w[b][k] /= s;
  }

  const int idx = n * DD + lane;
  float hd = h[idx], t1 = T1[idx], t2 = T2[idx], t3 = T3[idx], t4 = T4[idx];
#pragma unroll
  for (int b = 0; b < 3; ++b)
    s_res[slot][b][lane] =
        w[b][0] * hd + w[b][1] * t1 + w[b][2] * t2 + w[b][3] * t3 + w[b][4] * t4;
  __syncthreads();

#pragma unroll
  for (int b = 0; b < 3; ++b) {
    float y = projb[b * DD + lane];
#pragma unroll
    for (int j = 0; j < DD; ++j)
      y = fmaf(s_res[slot][b][j], projW[(b * DD + j) * DD + lane], y);
    float mu = g32_sum(y) * (1.0f / DD);
    float d = y - mu;
    float var = g32_sum(d * d) * (1.0f / DD);
    float z = d * rsqrtf(var + LNEPS) * projg[b * DD + lane] + projbeta[b * DD + lane];
    float pb = z / (1.0f + expf(-z));  // silu
    s_p[slot][b * DD + lane] = pb;
  }
  __syncthreads();

  float y = fusb1[lane];
#pragma unroll
  for (int j = 0; j < 3 * DD; ++j)
    y = fmaf(s_p[slot][j], fusW1[j * DD + lane], y);
  float mu = g32_sum(y) * (1.0f / DD);
  float d = y - mu;
  float var = g32_sum(d * d) * (1.0f / DD);
  float z = d * rsqrtf(var + LNEPS) * fusg[lane] + fusbeta[lane];
  float sv = z / (1.0f + expf(-z));
  s_s[slot][lane] = sv;
  __syncthreads();

  float o = fusb2[lane];
#pragma unroll
  for (int j = 0; j < DD; ++j)
    o = fmaf(s_s[slot][j], fusW2[j * DD + lane], o);
  out[idx] = hd + o;
}

extern "C" void kernel_launch(void* const* d_in, const int* in_sizes, int n_in,
                              void* d_out, int out_size, void* d_ws, size_t ws_size,
                              hipStream_t stream) {
  (void)in_sizes; (void)n_in; (void)out_size;
  const float* h        = (const float*)d_in[0];
  const float* Q        = (const float*)d_in[1];
  const int*   ei       = (const int*)d_in[2];
  const float* coeffs   = (const float*)d_in[3];
  const float* projW    = (const float*)d_in[4];
  const float* projb    = (const float*)d_in[5];
  const float* projg    = (const float*)d_in[6];
  const float* projbeta = (const float*)d_in[7];
  const float* fusW1    = (const float*)d_in[8];
  const float* fusb1    = (const float*)d_in[9];
  const float* fusg     = (const float*)d_in[10];
  const float* fusbeta  = (const float*)d_in[11];
  const float* fusW2    = (const float*)d_in[12];
  const float* fusb2    = (const float*)d_in[13];
  float* out = (float*)d_out;

  const size_t qh_bytes = (size_t)EE * DD * DD * sizeof(__half);  // 409.6 MB
  const size_t f32_elems = 6u * ND + NN + 64;
  const bool use_half = ws_size >= qh_bytes + f32_elems * sizeof(float);

  __half* Qh  = (__half*)d_ws;
  float* base = use_half ? (float*)((char*)d_ws + qh_bytes) : (float*)d_ws;
  float* uA   = base;             // [ND]
  float* uB   = uA + ND;          // [ND]
  float* T1   = uB + ND;          // [ND]
  float* T2   = T1 + ND;          // [ND]
  float* T3   = T2 + ND;          // [ND]
  float* T4   = T3 + ND;          // [ND]
  float* deg  = T4 + ND;          // [NN]
  float* scal = deg + NN;         // [64]

  hipMemsetAsync(deg, 0, (NN + 64) * sizeof(float), stream);

  k_deg<<<(EE + 255) / 256, 256, 0, stream>>>(ei, deg);
  k_genv<<<ND / 256, 256, 0, stream>>>(uA);

  // power iteration, unnormalized: u_{k+1} = L u_k
  float* cur = uA;
  float* nxt = uB;
  for (int it = 0; it < 5; ++it) {
    k_pre<<<ND / 256, 256, 0, stream>>>(cur, nullptr, deg, scal, nxt, 0);
    if (it == 0 && use_half)
      k_matvec_cvt<<<EE / 8, 256, 0, stream>>>(cur, Q, ei, nxt, Qh);
    else if (use_half)
      k_matvec_h<<<EE / 8, 256, 0, stream>>>(cur, Qh, ei, nxt, scal, 0, 1.0f);
    else
      k_matvec<<<EE / 8, 256, 0, stream>>>(cur, Q, ei, nxt, scal, 0, 1.0f);
    float* t = cur; cur = nxt; nxt = t;
  }
  // cur = u5, nxt = u4
  k_dots<<<DOT_BLOCKS, 256, 0, stream>>>(nxt, cur, scal);
  k_alpha<<<1, 1, 0, stream>>>(scal);

  // Chebyshev: T1 = alpha*L h - h ; T_next = 2*(alpha*L x - x) - xprev
  const float* xin[4]   = {h, T1, T2, T3};
  const float* prevs[4] = {nullptr, h, T1, T2};
  float* touts[4]       = {T1, T2, T3, T4};
  for (int k = 0; k < 4; ++k) {
    k_pre<<<ND / 256, 256, 0, stream>>>(xin[k], prevs[k], deg, scal, touts[k],
                                        k == 0 ? 1 : 2);
    float smul = (k == 0) ? 1.0f : 2.0f;
    if (use_half)
      k_matvec_h<<<EE / 8, 256, 0, stream>>>(xin[k], Qh, ei, touts[k], scal, 1, smul);
    else
      k_matvec<<<EE / 8, 256, 0, stream>>>(xin[k], Q, ei, touts[k], scal, 1, smul);
  }

  k_fuse<<<NN / 8, 256, 0, stream>>>(h, T1, T2, T3, T4, coeffs,
                                     projW, projb, projg, projbeta,
                                     fusW1, fusb1, fusg, fusbeta,
                                     fusW2, fusb2, out);
}

// Round 5
// 1038.597 us; speedup vs baseline: 5.7634x; 1.0703x over previous
//
#include <hip/hip_runtime.h>
#include <hip/hip_fp16.h>
#include <math.h>

#define NN 40000
#define EE 200000
#define DD 32
#define ND (NN * DD)        // 1,280,000
#define LNEPS 1e-5f

typedef float    fv4 __attribute__((ext_vector_type(4)));
typedef unsigned uv4 __attribute__((ext_vector_type(4)));

// scal slots — separate cache lines for atomically-updated slots
#define SLOT_S1    0    // u4 . u5
#define SLOT_S2    32   // u4 . u4
#define SLOT_ALPHA 48   // 2 / (lam + eps)

__device__ __forceinline__ void threefry2x32(unsigned k0, unsigned k1,
                                             unsigned x0, unsigned x1,
                                             unsigned& o0, unsigned& o1) {
  const unsigned k2 = k0 ^ k1 ^ 0x1BD11BDAu;
  unsigned v0 = x0 + k0, v1 = x1 + k1;
#define TF_ROUND(r) { v0 += v1; v1 = (v1 << (r)) | (v1 >> (32 - (r))); v1 ^= v0; }
  TF_ROUND(13) TF_ROUND(15) TF_ROUND(26) TF_ROUND(6)
  v0 += k1; v1 += k2 + 1u;
  TF_ROUND(17) TF_ROUND(29) TF_ROUND(16) TF_ROUND(24)
  v0 += k2; v1 += k0 + 2u;
  TF_ROUND(13) TF_ROUND(15) TF_ROUND(26) TF_ROUND(6)
  v0 += k0; v1 += k1 + 3u;
  TF_ROUND(17) TF_ROUND(29) TF_ROUND(16) TF_ROUND(24)
  v0 += k1; v1 += k2 + 4u;
  TF_ROUND(13) TF_ROUND(15) TF_ROUND(26) TF_ROUND(6)
  v0 += k2; v1 += k0 + 5u;
#undef TF_ROUND
  o0 = v0; o1 = v1;
}

__device__ __forceinline__ float wave64_sum(float x) {
  for (int o = 32; o > 0; o >>= 1) x += __shfl_xor(x, o, 64);
  return x;
}
__device__ __forceinline__ float g32_sum(float x) {
  for (int o = 16; o > 0; o >>= 1) x += __shfl_xor(x, o, 32);
  return x;
}

__global__ void k_deg(const int* __restrict__ ei, float* __restrict__ deg) {
  int e = blockIdx.x * 256 + threadIdx.x;
  if (e < EE) {
    atomicAdd(deg + ei[e], 1.0f);
    atomicAdd(deg + ei[EE + e], 1.0f);
  }
}

// v0 = N(0,1) via exact JAX threefry pipeline; normalization deferred (scale-free).
__global__ void k_genv(float* __restrict__ v) {
  int i = blockIdx.x * 256 + threadIdx.x;  // exact ND
  unsigned o0, o1;
  threefry2x32(0u, 42u, 0u, (unsigned)i, o0, o1);
  unsigned bits = o1;
  float f = __uint_as_float((bits >> 9) | 0x3f800000u) - 1.0f;  // [0,1)
  const float lo = -0.99999994f;                                 // nextafter(-1,0)
  float u = fmaxf(lo, f * 2.0f + lo);
  v[i] = 1.41421354f * erfinvf(u);
}

// out = diag part (+ Chebyshev affine terms); matvec then atomically subtracts Q-part.
__global__ void k_pre(const float* __restrict__ x, const float* __restrict__ xprev,
                      const float* __restrict__ deg, const float* __restrict__ scal,
                      float* __restrict__ out, int mode) {
  int i = blockIdx.x * 256 + threadIdx.x;
  float d = deg[i >> 5];
  float xi = x[i];
  if (mode == 0)       out[i] = d * xi;
  else if (mode == 1)  out[i] = scal[SLOT_ALPHA] * d * xi - xi;
  else                 out[i] = 2.0f * scal[SLOT_ALPHA] * d * xi - 2.0f * xi - xprev[i];
}

__device__ __forceinline__ int clamp8(float q) {
  int v = (int)rintf(q);
  return v < -127 ? -127 : (v > 127 ? 127 : v);
}
__device__ __forceinline__ unsigned pack4v(fv4 q, float inv) {
  int q0 = clamp8(q.x * inv), q1 = clamp8(q.y * inv),
      q2 = clamp8(q.z * inv), q3 = clamp8(q.w * inv);
  return (q0 & 255) | ((q1 & 255) << 8) | ((q2 & 255) << 16) | ((q3 & 255) << 24);
}
__device__ __forceinline__ void dp4(unsigned u, fv4 xv, float& acc) {
  acc = fmaf((float)(signed char)(u),        xv.x, acc);
  acc = fmaf((float)(signed char)(u >> 8),   xv.y, acc);
  acc = fmaf((float)(signed char)(u >> 16),  xv.z, acc);
  acc = fmaf((float)(signed char)(u >> 24),  xv.w, acc);
}

// f32 sweep (power iter #1), fused Q -> int8(per-row fp16 scale) for later sweeps.
__global__ __launch_bounds__(256) void k_matvec_cvt(const float* __restrict__ x,
                                                    const float* __restrict__ Q,
                                                    const int* __restrict__ ei,
                                                    float* __restrict__ out,
                                                    char* __restrict__ Qi8,
                                                    __half* __restrict__ Qs) {
  const int slot = threadIdx.x >> 5;
  const int lane = threadIdx.x & 31;
  const int e = blockIdx.x * 8 + slot;  // EE % 8 == 0
  const int row = ei[e];
  const int col = ei[EE + e];
  const fv4* __restrict__ x4 = (const fv4*)(x + (size_t)col * DD);
  fv4 xr[8];
#pragma unroll
  for (int k = 0; k < 8; ++k) xr[k] = x4[k];
  const fv4* __restrict__ q4 =
      (const fv4*)(Q + (size_t)e * (DD * DD) + (size_t)lane * DD);
  fv4 qf[8];
#pragma unroll
  for (int k = 0; k < 8; ++k) qf[k] = __builtin_nontemporal_load(q4 + k);
  float acc = 0.0f;
#pragma unroll
  for (int k = 0; k < 8; ++k) {
    acc = fmaf(qf[k].x, xr[k].x, acc);
    acc = fmaf(qf[k].y, xr[k].y, acc);
    acc = fmaf(qf[k].z, xr[k].z, acc);
    acc = fmaf(qf[k].w, xr[k].w, acc);
  }
  // per-row absmax -> fp16 scale -> int8 quantize against stored scale
  float m = 0.0f;
#pragma unroll
  for (int k = 0; k < 8; ++k) {
    m = fmaxf(m, fmaxf(fmaxf(fabsf(qf[k].x), fabsf(qf[k].y)),
                       fmaxf(fabsf(qf[k].z), fabsf(qf[k].w))));
  }
  __half sh = __float2half(m * (1.0f / 127.0f));
  float s = __half2float(sh);
  float inv = (s > 0.0f) ? 1.0f / s : 0.0f;
  uv4 pa, pb;
  pa.x = pack4v(qf[0], inv);
  pa.y = pack4v(qf[1], inv);
  pa.z = pack4v(qf[2], inv);
  pa.w = pack4v(qf[3], inv);
  pb.x = pack4v(qf[4], inv);
  pb.y = pack4v(qf[5], inv);
  pb.z = pack4v(qf[6], inv);
  pb.w = pack4v(qf[7], inv);
  uv4* __restrict__ qs = (uv4*)(Qi8 + (size_t)e * (DD * DD) + (size_t)lane * DD);
  __builtin_nontemporal_store(pa, qs);
  __builtin_nontemporal_store(pb, qs + 1);
  Qs[e * DD + lane] = sh;
  atomicAdd(out + (size_t)row * DD + lane, -acc);
}

// int8-Q sweep; f32 vectors and accumulation.
__global__ __launch_bounds__(256) void k_matvec_i8(const float* __restrict__ x,
                                                   const char* __restrict__ Qi8,
                                                   const __half* __restrict__ Qs,
                                                   const int* __restrict__ ei,
                                                   float* __restrict__ out,
                                                   const float* __restrict__ scal,
                                                   int use_alpha, float smul) {
  const int slot = threadIdx.x >> 5;
  const int lane = threadIdx.x & 31;
  const int e = blockIdx.x * 8 + slot;
  const float factor = use_alpha ? scal[SLOT_ALPHA] * smul : smul;
  const int row = ei[e];
  const int col = ei[EE + e];
  const fv4* __restrict__ x4 = (const fv4*)(x + (size_t)col * DD);
  fv4 xr[8];
#pragma unroll
  for (int k = 0; k < 8; ++k) xr[k] = x4[k];
  const uv4* __restrict__ q8 =
      (const uv4*)(Qi8 + (size_t)e * (DD * DD) + (size_t)lane * DD);
  uv4 pa = __builtin_nontemporal_load(q8);
  uv4 pb = __builtin_nontemporal_load(q8 + 1);
  float s = __half2float(Qs[e * DD + lane]);
  float acc = 0.0f;
  dp4(pa.x, xr[0], acc); dp4(pa.y, xr[1], acc);
  dp4(pa.z, xr[2], acc); dp4(pa.w, xr[3], acc);
  dp4(pb.x, xr[4], acc); dp4(pb.y, xr[5], acc);
  dp4(pb.z, xr[6], acc); dp4(pb.w, xr[7], acc);
  atomicAdd(out + (size_t)row * DD + lane, -factor * s * acc);
}

// f32 fallback (only used if ws_size is too small for the int8 Q copy)
__global__ __launch_bounds__(256) void k_matvec(const float* __restrict__ x,
                                                const float* __restrict__ Q,
                                                const int* __restrict__ ei,
                                                float* __restrict__ out,
                                                const float* __restrict__ scal,
                                                int use_alpha, float smul) {
  const int slot = threadIdx.x >> 5;
  const int lane = threadIdx.x & 31;
  const int e = blockIdx.x * 8 + slot;
  const float factor = use_alpha ? scal[SLOT_ALPHA] * smul : smul;
  const int row = ei[e];
  const int col = ei[EE + e];
  const fv4* __restrict__ x4 = (const fv4*)(x + (size_t)col * DD);
  fv4 xr[8];
#pragma unroll
  for (int k = 0; k < 8; ++k) xr[k] = x4[k];
  const fv4* __restrict__ q4 =
      (const fv4*)(Q + (size_t)e * (DD * DD) + (size_t)lane * DD);
  float acc = 0.0f;
#pragma unroll
  for (int k = 0; k < 8; ++k) {
    fv4 q = q4[k];
    acc = fmaf(q.x, xr[k].x, acc);
    acc = fmaf(q.y, xr[k].y, acc);
    acc = fmaf(q.z, xr[k].z, acc);
    acc = fmaf(q.w, xr[k].w, acc);
  }
  atomicAdd(out + (size_t)row * DD + lane, -factor * acc);
}

#define DOT_BLOCKS 640
__global__ void k_dots(const float* __restrict__ u4, const float* __restrict__ u5,
                       float* __restrict__ scal) {
  float s1 = 0.0f, s2 = 0.0f;
  for (int i = blockIdx.x * 256 + threadIdx.x; i < ND; i += DOT_BLOCKS * 256) {
    float a = u4[i], b = u5[i];
    s1 = fmaf(a, b, s1);
    s2 = fmaf(a, a, s2);
  }
  s1 = wave64_sum(s1);
  s2 = wave64_sum(s2);
  __shared__ float ls1[4], ls2[4];
  int w = threadIdx.x >> 6;
  if ((threadIdx.x & 63) == 0) { ls1[w] = s1; ls2[w] = s2; }
  __syncthreads();
  if (threadIdx.x == 0) {
    atomicAdd(scal + SLOT_S1, ls1[0] + ls1[1] + ls1[2] + ls1[3]);
    atomicAdd(scal + SLOT_S2, ls2[0] + ls2[1] + ls2[2] + ls2[3]);
  }
}

__global__ void k_alpha(float* __restrict__ scal) {
  float lam = scal[SLOT_S1] / scal[SLOT_S2] / (1.0f + 1e-8f);
  lam = fmaxf(lam, 1.0f);
  scal[SLOT_ALPHA] = 2.0f / (lam + 1e-8f);
}

__global__ __launch_bounds__(256) void k_fuse(
    const float* __restrict__ h,
    const float* __restrict__ T1, const float* __restrict__ T2,
    const float* __restrict__ T3, const float* __restrict__ T4,
    const float* __restrict__ coeffs,
    const float* __restrict__ projW, const float* __restrict__ projb,
    const float* __restrict__ projg, const float* __restrict__ projbeta,
    const float* __restrict__ fusW1, const float* __restrict__ fusb1,
    const float* __restrict__ fusg, const float* __restrict__ fusbeta,
    const float* __restrict__ fusW2, const float* __restrict__ fusb2,
    float* __restrict__ out) {
  __shared__ float s_res[8][3][DD];
  __shared__ float s_p[8][3 * DD];
  __shared__ float s_s[8][DD];
  const int slot = threadIdx.x >> 5;
  const int lane = threadIdx.x & 31;
  const int n = blockIdx.x * 8 + slot;  // 5000 blocks exact

  float w[3][5];
#pragma unroll
  for (int b = 0; b < 3; ++b) {
    float m = -1e30f;
#pragma unroll
    for (int k = 0; k < 5; ++k) m = fmaxf(m, coeffs[b * 5 + k]);
    float s = 0.0f;
#pragma unroll
    for (int k = 0; k < 5; ++k) { w[b][k] = expf(coeffs[b * 5 + k] - m); s += w[b][k]; }
#pragma unroll
    for (int k = 0; k < 5; ++k) w[b][k] /= s;
  }

  const int idx = n * DD + lane;
  float hd = h[idx], t1 = T1[idx], t2 = T2[idx], t3 = T3[idx], t4 = T4[idx];
#pragma unroll
  for (int b = 0; b < 3; ++b)
    s_res[slot][b][lane] =
        w[b][0] * hd + w[b][1] * t1 + w[b][2] * t2 + w[b][3] * t3 + w[b][4] * t4;
  __syncthreads();

#pragma unroll
  for (int b = 0; b < 3; ++b) {
    float y = projb[b * DD + lane];
#pragma unroll
    for (int j = 0; j < DD; ++j)
      y = fmaf(s_res[slot][b][j], projW[(b * DD + j) * DD + lane], y);
    float mu = g32_sum(y) * (1.0f / DD);
    float d = y - mu;
    float var = g32_sum(d * d) * (1.0f / DD);
    float z = d * rsqrtf(var + LNEPS) * projg[b * DD + lane] + projbeta[b * DD + lane];
    float pb = z / (1.0f + expf(-z));  // silu
    s_p[slot][b * DD + lane] = pb;
  }
  __syncthreads();

  float y = fusb1[lane];
#pragma unroll
  for (int j = 0; j < 3 * DD; ++j)
    y = fmaf(s_p[slot][j], fusW1[j * DD + lane], y);
  float mu = g32_sum(y) * (1.0f / DD);
  float d = y - mu;
  float var = g32_sum(d * d) * (1.0f / DD);
  float z = d * rsqrtf(var + LNEPS) * fusg[lane] + fusbeta[lane];
  float sv = z / (1.0f + expf(-z));
  s_s[slot][lane] = sv;
  __syncthreads();

  float o = fusb2[lane];
#pragma unroll
  for (int j = 0; j < DD; ++j)
    o = fmaf(s_s[slot][j], fusW2[j * DD + lane], o);
  out[idx] = hd + o;
}

extern "C" void kernel_launch(void* const* d_in, const int* in_sizes, int n_in,
                              void* d_out, int out_size, void* d_ws, size_t ws_size,
                              hipStream_t stream) {
  (void)in_sizes; (void)n_in; (void)out_size;
  const float* h        = (const float*)d_in[0];
  const float* Q        = (const float*)d_in[1];
  const int*   ei       = (const int*)d_in[2];
  const float* coeffs   = (const float*)d_in[3];
  const float* projW    = (const float*)d_in[4];
  const float* projb    = (const float*)d_in[5];
  const float* projg    = (const float*)d_in[6];
  const float* projbeta = (const float*)d_in[7];
  const float* fusW1    = (const float*)d_in[8];
  const float* fusb1    = (const float*)d_in[9];
  const float* fusg     = (const float*)d_in[10];
  const float* fusbeta  = (const float*)d_in[11];
  const float* fusW2    = (const float*)d_in[12];
  const float* fusb2    = (const float*)d_in[13];
  float* out = (float*)d_out;

  const size_t qi_bytes = (size_t)EE * DD * DD;                 // 204.8 MB
  const size_t qs_bytes = (size_t)EE * DD * sizeof(__half);     // 12.8 MB
  const size_t f32_elems = 6u * ND + NN + 64;
  const bool use_i8 = ws_size >= qi_bytes + qs_bytes + f32_elems * sizeof(float);

  char*   Qi8 = (char*)d_ws;
  __half* Qs  = (__half*)((char*)d_ws + qi_bytes);
  float* base = use_i8 ? (float*)((char*)d_ws + qi_bytes + qs_bytes) : (float*)d_ws;
  float* uA   = base;             // [ND]
  float* uB   = uA + ND;          // [ND]
  float* T1   = uB + ND;          // [ND]
  float* T2   = T1 + ND;          // [ND]
  float* T3   = T2 + ND;          // [ND]
  float* T4   = T3 + ND;          // [ND]
  float* deg  = T4 + ND;          // [NN]
  float* scal = deg + NN;         // [64]

  (void)hipMemsetAsync(deg, 0, (NN + 64) * sizeof(float), stream);

  k_deg<<<(EE + 255) / 256, 256, 0, stream>>>(ei, deg);
  k_genv<<<ND / 256, 256, 0, stream>>>(uA);

  // power iteration, unnormalized: u_{k+1} = L u_k
  float* cur = uA;
  float* nxt = uB;
  for (int it = 0; it < 5; ++it) {
    k_pre<<<ND / 256, 256, 0, stream>>>(cur, nullptr, deg, scal, nxt, 0);
    if (it == 0 && use_i8)
      k_matvec_cvt<<<EE / 8, 256, 0, stream>>>(cur, Q, ei, nxt, Qi8, Qs);
    else if (use_i8)
      k_matvec_i8<<<EE / 8, 256, 0, stream>>>(cur, Qi8, Qs, ei, nxt, scal, 0, 1.0f);
    else
      k_matvec<<<EE / 8, 256, 0, stream>>>(cur, Q, ei, nxt, scal, 0, 1.0f);
    float* t = cur; cur = nxt; nxt = t;
  }
  // cur = u5, nxt = u4
  k_dots<<<DOT_BLOCKS, 256, 0, stream>>>(nxt, cur, scal);
  k_alpha<<<1, 1, 0, stream>>>(scal);

  // Chebyshev: T1 = alpha*L h - h ; T_next = 2*(alpha*L x - x) - xprev
  const float* xin[4]   = {h, T1, T2, T3};
  const float* prevs[4] = {nullptr, h, T1, T2};
  float* touts[4]       = {T1, T2, T3, T4};
  for (int k = 0; k < 4; ++k) {
    k_pre<<<ND / 256, 256, 0, stream>>>(xin[k], prevs[k], deg, scal, touts[k],
                                        k == 0 ? 1 : 2);
    float smul = (k == 0) ? 1.0f : 2.0f;
    if (use_i8)
      k_matvec_i8<<<EE / 8, 256, 0, stream>>>(xin[k], Qi8, Qs, ei, touts[k], scal, 1, smul);
    else
      k_matvec<<<EE / 8, 256, 0, stream>>>(xin[k], Q, ei, touts[k], scal, 1, smul);
  }

  k_fuse<<<NN / 8, 256, 0, stream>>>(h, T1, T2, T3, T4, coeffs,
                                     projW, projb, projg, projbeta,
                                     fusW1, fusb1, fusg, fusbeta,
                                     fusW2, fusb2, out);
}

// Round 6
// 1036.842 us; speedup vs baseline: 5.7731x; 1.0017x over previous
//
#include <hip/hip_runtime.h>
#include <hip/hip_fp16.h>
#include <math.h>

#define NN 40000
#define EE 200000
#define DD 32
#define ND (NN * DD)        // 1,280,000
#define LNEPS 1e-5f

typedef float    fv4 __attribute__((ext_vector_type(4)));
typedef unsigned uv4 __attribute__((ext_vector_type(4)));

// scal slots — separate cache lines for atomically-updated slots
#define SLOT_S1    0    // u4 . u5
#define SLOT_S2    32   // u4 . u4
#define SLOT_ALPHA 48   // 2 / (lam + eps)

__device__ __forceinline__ void threefry2x32(unsigned k0, unsigned k1,
                                             unsigned x0, unsigned x1,
                                             unsigned& o0, unsigned& o1) {
  const unsigned k2 = k0 ^ k1 ^ 0x1BD11BDAu;
  unsigned v0 = x0 + k0, v1 = x1 + k1;
#define TF_ROUND(r) { v0 += v1; v1 = (v1 << (r)) | (v1 >> (32 - (r))); v1 ^= v0; }
  TF_ROUND(13) TF_ROUND(15) TF_ROUND(26) TF_ROUND(6)
  v0 += k1; v1 += k2 + 1u;
  TF_ROUND(17) TF_ROUND(29) TF_ROUND(16) TF_ROUND(24)
  v0 += k2; v1 += k0 + 2u;
  TF_ROUND(13) TF_ROUND(15) TF_ROUND(26) TF_ROUND(6)
  v0 += k0; v1 += k1 + 3u;
  TF_ROUND(17) TF_ROUND(29) TF_ROUND(16) TF_ROUND(24)
  v0 += k1; v1 += k2 + 4u;
  TF_ROUND(13) TF_ROUND(15) TF_ROUND(26) TF_ROUND(6)
  v0 += k2; v1 += k0 + 5u;
#undef TF_ROUND
  o0 = v0; o1 = v1;
}

__device__ __forceinline__ float wave64_sum(float x) {
  for (int o = 32; o > 0; o >>= 1) x += __shfl_xor(x, o, 64);
  return x;
}
__device__ __forceinline__ float g32_sum(float x) {
  for (int o = 16; o > 0; o >>= 1) x += __shfl_xor(x, o, 32);
  return x;
}

// deg (float, counts both endpoints) + hist (int, counts row occurrences)
__global__ void k_deg(const int* __restrict__ ei, float* __restrict__ deg,
                      int* __restrict__ hist) {
  int e = blockIdx.x * 256 + threadIdx.x;
  if (e < EE) {
    int r = ei[e];
    atomicAdd(deg + r, 1.0f);
    atomicAdd(deg + ei[EE + e], 1.0f);
    atomicAdd(hist + r, 1);
  }
}

// single-block exclusive scan over hist[NN] -> row_start[NN+1], cursor[NN]
__global__ __launch_bounds__(1024) void k_scan(const int* __restrict__ hist,
                                               int* __restrict__ row_start,
                                               int* __restrict__ cursor) {
  __shared__ int part[1024];
  const int t = threadIdx.x;
  const int base = t * 40;              // 1024*40 >= NN
  int s = 0;
  for (int i = base; i < base + 40 && i < NN; ++i) s += hist[i];
  part[t] = s;
  __syncthreads();
  for (int off = 1; off < 1024; off <<= 1) {
    int v = (t >= off) ? part[t - off] : 0;
    __syncthreads();
    part[t] += v;
    __syncthreads();
  }
  int ex = (t == 0) ? 0 : part[t - 1];
  for (int i = base; i < base + 40 && i < NN; ++i) {
    row_start[i] = ex;
    cursor[i] = ex;
    ex += hist[i];
  }
  if (t == 0) row_start[NN] = EE;
}

// v0 = N(0,1) via exact JAX threefry pipeline; normalization deferred (scale-free).
__global__ void k_genv(float* __restrict__ v) {
  int i = blockIdx.x * 256 + threadIdx.x;  // exact ND
  unsigned o0, o1;
  threefry2x32(0u, 42u, 0u, (unsigned)i, o0, o1);
  unsigned bits = o1;
  float f = __uint_as_float((bits >> 9) | 0x3f800000u) - 1.0f;  // [0,1)
  const float lo = -0.99999994f;                                 // nextafter(-1,0)
  float u = fmaxf(lo, f * 2.0f + lo);
  v[i] = 1.41421354f * erfinvf(u);
}

__device__ __forceinline__ int clamp8(float q) {
  int v = (int)rintf(q);
  return v < -127 ? -127 : (v > 127 ? 127 : v);
}
__device__ __forceinline__ unsigned pack4v(fv4 q, float inv) {
  int q0 = clamp8(q.x * inv), q1 = clamp8(q.y * inv),
      q2 = clamp8(q.z * inv), q3 = clamp8(q.w * inv);
  return (q0 & 255) | ((q1 & 255) << 8) | ((q2 & 255) << 16) | ((q3 & 255) << 24);
}
__device__ __forceinline__ void dp4(unsigned u, fv4 xv, float& acc) {
  acc = fmaf((float)(signed char)(u),        xv.x, acc);
  acc = fmaf((float)(signed char)(u >> 8),   xv.y, acc);
  acc = fmaf((float)(signed char)(u >> 16),  xv.z, acc);
  acc = fmaf((float)(signed char)(u >> 24),  xv.w, acc);
}

// Convert Q -> int8 (per-row fp16 scale), writing into row-sorted CSR position.
__global__ __launch_bounds__(256) void k_cvt(const float* __restrict__ Q,
                                             const int* __restrict__ ei,
                                             int* __restrict__ cursor,
                                             char* __restrict__ Qi8,
                                             __half* __restrict__ Qs,
                                             int* __restrict__ cols) {
  const int slot = threadIdx.x >> 5;
  const int lane = threadIdx.x & 31;
  const int e = blockIdx.x * 8 + slot;  // EE % 8 == 0
  const int row = ei[e];
  const int col = ei[EE + e];
  int pos = 0;
  if (lane == 0) pos = atomicAdd(cursor + row, 1);
  pos = __shfl(pos, 0, 32);
  const fv4* __restrict__ q4 =
      (const fv4*)(Q + (size_t)e * (DD * DD) + (size_t)lane * DD);
  fv4 qf[8];
#pragma unroll
  for (int k = 0; k < 8; ++k) qf[k] = __builtin_nontemporal_load(q4 + k);
  float m = 0.0f;
#pragma unroll
  for (int k = 0; k < 8; ++k) {
    m = fmaxf(m, fmaxf(fmaxf(fabsf(qf[k].x), fabsf(qf[k].y)),
                       fmaxf(fabsf(qf[k].z), fabsf(qf[k].w))));
  }
  __half sh = __float2half(m * (1.0f / 127.0f));
  float s = __half2float(sh);
  float inv = (s > 0.0f) ? 1.0f / s : 0.0f;
  uv4 pa, pb;
  pa.x = pack4v(qf[0], inv); pa.y = pack4v(qf[1], inv);
  pa.z = pack4v(qf[2], inv); pa.w = pack4v(qf[3], inv);
  pb.x = pack4v(qf[4], inv); pb.y = pack4v(qf[5], inv);
  pb.z = pack4v(qf[6], inv); pb.w = pack4v(qf[7], inv);
  uv4* __restrict__ qs = (uv4*)(Qi8 + (size_t)pos * (DD * DD) + (size_t)lane * DD);
  qs[0] = pa;   // cached stores: sorted Q copy (218 MB) may stay L3-resident
  qs[1] = pb;
  Qs[pos * DD + lane] = sh;
  if (lane == 0) cols[pos] = col;
}

// Gather-form matvec + fused diag/Chebyshev epilogue. 32 lanes per node.
// mode 0: out = deg*x - off
// mode 1: out = alpha*(deg*x - off) - x
// mode 2: out = 2*alpha*(deg*x - off) - 2x - xprev
__global__ __launch_bounds__(256) void k_gather(const float* __restrict__ x,
                                                const float* __restrict__ xprev,
                                                const char* __restrict__ Qi8,
                                                const __half* __restrict__ Qs,
                                                const int* __restrict__ cols,
                                                const int* __restrict__ row_start,
                                                const float* __restrict__ deg,
                                                const float* __restrict__ scal,
                                                float* __restrict__ out, int mode) {
  const int slot = threadIdx.x >> 5;
  const int lane = threadIdx.x & 31;
  const int r = blockIdx.x * 8 + slot;  // NN % 8 == 0
  const int beg = row_start[r];
  const int end = row_start[r + 1];
  float off_acc = 0.0f;
  for (int p = beg; p < end; ++p) {
    const int col = cols[p];
    const fv4* __restrict__ x4 = (const fv4*)(x + (size_t)col * DD);
    fv4 xr[8];
#pragma unroll
    for (int k = 0; k < 8; ++k) xr[k] = x4[k];
    const uv4* __restrict__ q8 =
        (const uv4*)(Qi8 + (size_t)p * (DD * DD) + (size_t)lane * DD);
    uv4 pa = q8[0];
    uv4 pb = q8[1];
    float s = __half2float(Qs[p * DD + lane]);
    float d = 0.0f;
    dp4(pa.x, xr[0], d); dp4(pa.y, xr[1], d);
    dp4(pa.z, xr[2], d); dp4(pa.w, xr[3], d);
    dp4(pb.x, xr[4], d); dp4(pb.y, xr[5], d);
    dp4(pb.z, xr[6], d); dp4(pb.w, xr[7], d);
    off_acc = fmaf(s, d, off_acc);
  }
  const size_t idx = (size_t)r * DD + lane;
  const float xi = x[idx];
  const float dv = deg[r];
  float o;
  if (mode == 0)      o = dv * xi - off_acc;
  else if (mode == 1) o = scal[SLOT_ALPHA] * (dv * xi - off_acc) - xi;
  else                o = 2.0f * scal[SLOT_ALPHA] * (dv * xi - off_acc)
                          - 2.0f * xi - xprev[idx];
  out[idx] = o;
}

// f32 fallback matvec pieces (only if ws_size too small for the CSR copy)
__global__ void k_pre(const float* __restrict__ x, const float* __restrict__ xprev,
                      const float* __restrict__ deg, const float* __restrict__ scal,
                      float* __restrict__ out, int mode) {
  int i = blockIdx.x * 256 + threadIdx.x;
  float d = deg[i >> 5];
  float xi = x[i];
  if (mode == 0)       out[i] = d * xi;
  else if (mode == 1)  out[i] = scal[SLOT_ALPHA] * d * xi - xi;
  else                 out[i] = 2.0f * scal[SLOT_ALPHA] * d * xi - 2.0f * xi - xprev[i];
}

__global__ __launch_bounds__(256) void k_matvec(const float* __restrict__ x,
                                                const float* __restrict__ Q,
                                                const int* __restrict__ ei,
                                                float* __restrict__ out,
                                                const float* __restrict__ scal,
                                                int use_alpha, float smul) {
  const int slot = threadIdx.x >> 5;
  const int lane = threadIdx.x & 31;
  const int e = blockIdx.x * 8 + slot;
  const float factor = use_alpha ? scal[SLOT_ALPHA] * smul : smul;
  const int row = ei[e];
  const int col = ei[EE + e];
  const fv4* __restrict__ x4 = (const fv4*)(x + (size_t)col * DD);
  fv4 xr[8];
#pragma unroll
  for (int k = 0; k < 8; ++k) xr[k] = x4[k];
  const fv4* __restrict__ q4 =
      (const fv4*)(Q + (size_t)e * (DD * DD) + (size_t)lane * DD);
  float acc = 0.0f;
#pragma unroll
  for (int k = 0; k < 8; ++k) {
    fv4 q = q4[k];
    acc = fmaf(q.x, xr[k].x, acc);
    acc = fmaf(q.y, xr[k].y, acc);
    acc = fmaf(q.z, xr[k].z, acc);
    acc = fmaf(q.w, xr[k].w, acc);
  }
  atomicAdd(out + (size_t)row * DD + lane, -factor * acc);
}

#define DOT_BLOCKS 640
__global__ void k_dots(const float* __restrict__ u4, const float* __restrict__ u5,
                       float* __restrict__ scal) {
  float s1 = 0.0f, s2 = 0.0f;
  for (int i = blockIdx.x * 256 + threadIdx.x; i < ND; i += DOT_BLOCKS * 256) {
    float a = u4[i], b = u5[i];
    s1 = fmaf(a, b, s1);
    s2 = fmaf(a, a, s2);
  }
  s1 = wave64_sum(s1);
  s2 = wave64_sum(s2);
  __shared__ float ls1[4], ls2[4];
  int w = threadIdx.x >> 6;
  if ((threadIdx.x & 63) == 0) { ls1[w] = s1; ls2[w] = s2; }
  __syncthreads();
  if (threadIdx.x == 0) {
    atomicAdd(scal + SLOT_S1, ls1[0] + ls1[1] + ls1[2] + ls1[3]);
    atomicAdd(scal + SLOT_S2, ls2[0] + ls2[1] + ls2[2] + ls2[3]);
  }
}

__global__ void k_alpha(float* __restrict__ scal) {
  float lam = scal[SLOT_S1] / scal[SLOT_S2] / (1.0f + 1e-8f);
  lam = fmaxf(lam, 1.0f);
  scal[SLOT_ALPHA] = 2.0f / (lam + 1e-8f);
}

__global__ __launch_bounds__(256) void k_fuse(
    const float* __restrict__ h,
    const float* __restrict__ T1, const float* __restrict__ T2,
    const float* __restrict__ T3, const float* __restrict__ T4,
    const float* __restrict__ coeffs,
    const float* __restrict__ projW, const float* __restrict__ projb,
    const float* __restrict__ projg, const float* __restrict__ projbeta,
    const float* __restrict__ fusW1, const float* __restrict__ fusb1,
    const float* __restrict__ fusg, const float* __restrict__ fusbeta,
    const float* __restrict__ fusW2, const float* __restrict__ fusb2,
    float* __restrict__ out) {
  __shared__ float s_res[8][3][DD];
  __shared__ float s_p[8][3 * DD];
  __shared__ float s_s[8][DD];
  const int slot = threadIdx.x >> 5;
  const int lane = threadIdx.x & 31;
  const int n = blockIdx.x * 8 + slot;  // 5000 blocks exact

  float w[3][5];
#pragma unroll
  for (int b = 0; b < 3; ++b) {
    float m = -1e30f;
#pragma unroll
    for (int k = 0; k < 5; ++k) m = fmaxf(m, coeffs[b * 5 + k]);
    float s = 0.0f;
#pragma unroll
    for (int k = 0; k < 5; ++k) { w[b][k] = expf(coeffs[b * 5 + k] - m); s += w[b][k]; }
#pragma unroll
    for (int k = 0; k < 5; ++k) w[b][k] /= s;
  }

  const int idx = n * DD + lane;
  float hd = h[idx], t1 = T1[idx], t2 = T2[idx], t3 = T3[idx], t4 = T4[idx];
#pragma unroll
  for (int b = 0; b < 3; ++b)
    s_res[slot][b][lane] =
        w[b][0] * hd + w[b][1] * t1 + w[b][2] * t2 + w[b][3] * t3 + w[b][4] * t4;
  __syncthreads();

#pragma unroll
  for (int b = 0; b < 3; ++b) {
    float y = projb[b * DD + lane];
#pragma unroll
    for (int j = 0; j < DD; ++j)
      y = fmaf(s_res[slot][b][j], projW[(b * DD + j) * DD + lane], y);
    float mu = g32_sum(y) * (1.0f / DD);
    float d = y - mu;
    float var = g32_sum(d * d) * (1.0f / DD);
    float z = d * rsqrtf(var + LNEPS) * projg[b * DD + lane] + projbeta[b * DD + lane];
    float pb = z / (1.0f + expf(-z));  // silu
    s_p[slot][b * DD + lane] = pb;
  }
  __syncthreads();

  float y = fusb1[lane];
#pragma unroll
  for (int j = 0; j < 3 * DD; ++j)
    y = fmaf(s_p[slot][j], fusW1[j * DD + lane], y);
  float mu = g32_sum(y) * (1.0f / DD);
  float d = y - mu;
  float var = g32_sum(d * d) * (1.0f / DD);
  float z = d * rsqrtf(var + LNEPS) * fusg[lane] + fusbeta[lane];
  float sv = z / (1.0f + expf(-z));
  s_s[slot][lane] = sv;
  __syncthreads();

  float o = fusb2[lane];
#pragma unroll
  for (int j = 0; j < DD; ++j)
    o = fmaf(s_s[slot][j], fusW2[j * DD + lane], o);
  out[idx] = hd + o;
}

extern "C" void kernel_launch(void* const* d_in, const int* in_sizes, int n_in,
                              void* d_out, int out_size, void* d_ws, size_t ws_size,
                              hipStream_t stream) {
  (void)in_sizes; (void)n_in; (void)out_size;
  const float* h        = (const float*)d_in[0];
  const float* Q        = (const float*)d_in[1];
  const int*   ei       = (const int*)d_in[2];
  const float* coeffs   = (const float*)d_in[3];
  const float* projW    = (const float*)d_in[4];
  const float* projb    = (const float*)d_in[5];
  const float* projg    = (const float*)d_in[6];
  const float* projbeta = (const float*)d_in[7];
  const float* fusW1    = (const float*)d_in[8];
  const float* fusb1    = (const float*)d_in[9];
  const float* fusg     = (const float*)d_in[10];
  const float* fusbeta  = (const float*)d_in[11];
  const float* fusW2    = (const float*)d_in[12];
  const float* fusb2    = (const float*)d_in[13];
  float* out = (float*)d_out;

  // workspace layout
  const size_t qi_bytes  = (size_t)EE * DD * DD;              // 204.8 MB
  const size_t qs_bytes  = (size_t)EE * DD * sizeof(__half);  // 12.8 MB
  const size_t col_bytes = (size_t)EE * sizeof(int);          // 0.8 MB
  const size_t idx_bytes = (size_t)(3 * NN + 2) * sizeof(int);
  const size_t f32_elems = 6u * (size_t)ND + NN + 64;
  const size_t need = qi_bytes + qs_bytes + col_bytes + idx_bytes +
                      f32_elems * sizeof(float) + 256;
  const bool fast = ws_size >= need;

  char*   Qi8 = (char*)d_ws;
  __half* Qs  = (__half*)((char*)d_ws + qi_bytes);
  int*  cols      = (int*)((char*)d_ws + qi_bytes + qs_bytes);
  int*  row_start = cols + EE;            // NN+1
  int*  cursor    = row_start + NN + 1;   // NN
  float* base = fast
      ? (float*)((char*)d_ws + ((qi_bytes + qs_bytes + col_bytes + idx_bytes + 255) & ~(size_t)255))
      : (float*)d_ws;
  float* uA   = base;             // [ND]
  float* uB   = uA + ND;          // [ND]
  float* T1   = uB + ND;          // [ND]
  float* T2   = T1 + ND;          // [ND]
  float* T3   = T2 + ND;          // [ND]
  float* T4   = T3 + ND;          // [ND]
  float* deg  = T4 + ND;          // [NN]
  float* scal = deg + NN;         // [64]
  int*   hist = (int*)(scal + 64);  // [NN] — zeroed together with deg/scal

  (void)hipMemsetAsync(deg, 0, (2 * NN + 64) * sizeof(float), stream);

  k_deg<<<(EE + 255) / 256, 256, 0, stream>>>(ei, deg, hist);
  k_genv<<<ND / 256, 256, 0, stream>>>(uA);

  if (fast) {
    k_scan<<<1, 1024, 0, stream>>>(hist, row_start, cursor);
    k_cvt<<<EE / 8, 256, 0, stream>>>(Q, ei, cursor, Qi8, Qs, cols);

    // power iteration, unnormalized: u_{k+1} = L u_k
    float* cur = uA;
    float* nxt = uB;
    for (int it = 0; it < 5; ++it) {
      k_gather<<<NN / 8, 256, 0, stream>>>(cur, nullptr, Qi8, Qs, cols,
                                           row_start, deg, scal, nxt, 0);
      float* t = cur; cur = nxt; nxt = t;
    }
    k_dots<<<DOT_BLOCKS, 256, 0, stream>>>(nxt, cur, scal);
    k_alpha<<<1, 1, 0, stream>>>(scal);

    // Chebyshev: T1 = alpha*L h - h ; T_next = 2*(alpha*L x - x) - xprev
    const float* xin[4]   = {h, T1, T2, T3};
    const float* prevs[4] = {nullptr, h, T1, T2};
    float* touts[4]       = {T1, T2, T3, T4};
    for (int k = 0; k < 4; ++k) {
      k_gather<<<NN / 8, 256, 0, stream>>>(xin[k], prevs[k], Qi8, Qs, cols,
                                           row_start, deg, scal, touts[k],
                                           k == 0 ? 1 : 2);
    }
  } else {
    // f32 atomic-scatter fallback
    float* cur = uA;
    float* nxt = uB;
    for (int it = 0; it < 5; ++it) {
      k_pre<<<ND / 256, 256, 0, stream>>>(cur, nullptr, deg, scal, nxt, 0);
      k_matvec<<<EE / 8, 256, 0, stream>>>(cur, Q, ei, nxt, scal, 0, 1.0f);
      float* t = cur; cur = nxt; nxt = t;
    }
    k_dots<<<DOT_BLOCKS, 256, 0, stream>>>(nxt, cur, scal);
    k_alpha<<<1, 1, 0, stream>>>(scal);
    const float* xin[4]   = {h, T1, T2, T3};
    const float* prevs[4] = {nullptr, h, T1, T2};
    float* touts[4]       = {T1, T2, T3, T4};
    for (int k = 0; k < 4; ++k) {
      k_pre<<<ND / 256, 256, 0, stream>>>(xin[k], prevs[k], deg, scal, touts[k],
                                          k == 0 ? 1 : 2);
      k_matvec<<<EE / 8, 256, 0, stream>>>(xin[k], Q, ei, touts[k], scal, 1,
                                           k == 0 ? 1.0f : 2.0f);
    }
  }

  k_fuse<<<NN / 8, 256, 0, stream>>>(h, T1, T2, T3, T4, coeffs,
                                     projW, projb, projg, projbeta,
                                     fusW1, fusb1, fusg, fusbeta,
                                     fusW2, fusb2, out);
}

// Round 7
// 983.881 us; speedup vs baseline: 6.0839x; 1.0538x over previous
//
#include <hip/hip_runtime.h>
#include <hip/hip_fp16.h>
#include <math.h>

#define NN 40000
#define EE 200000
#define DD 32
#define ND (NN * DD)        // 1,280,000
#define LNEPS 1e-5f

typedef float    fv4 __attribute__((ext_vector_type(4)));
typedef unsigned uv4 __attribute__((ext_vector_type(4)));

// scal slots — separate cache lines for atomically-updated slots
#define SLOT_S1    0    // u4 . u5
#define SLOT_S2    32   // u4 . u4
#define SLOT_ALPHA 48   // 2 / (lam + eps)

__device__ __forceinline__ void threefry2x32(unsigned k0, unsigned k1,
                                             unsigned x0, unsigned x1,
                                             unsigned& o0, unsigned& o1) {
  const unsigned k2 = k0 ^ k1 ^ 0x1BD11BDAu;
  unsigned v0 = x0 + k0, v1 = x1 + k1;
#define TF_ROUND(r) { v0 += v1; v1 = (v1 << (r)) | (v1 >> (32 - (r))); v1 ^= v0; }
  TF_ROUND(13) TF_ROUND(15) TF_ROUND(26) TF_ROUND(6)
  v0 += k1; v1 += k2 + 1u;
  TF_ROUND(17) TF_ROUND(29) TF_ROUND(16) TF_ROUND(24)
  v0 += k2; v1 += k0 + 2u;
  TF_ROUND(13) TF_ROUND(15) TF_ROUND(26) TF_ROUND(6)
  v0 += k0; v1 += k1 + 3u;
  TF_ROUND(17) TF_ROUND(29) TF_ROUND(16) TF_ROUND(24)
  v0 += k1; v1 += k2 + 4u;
  TF_ROUND(13) TF_ROUND(15) TF_ROUND(26) TF_ROUND(6)
  v0 += k2; v1 += k0 + 5u;
#undef TF_ROUND
  o0 = v0; o1 = v1;
}

__device__ __forceinline__ float wave64_sum(float x) {
  for (int o = 32; o > 0; o >>= 1) x += __shfl_xor(x, o, 64);
  return x;
}
__device__ __forceinline__ float g32_sum(float x) {
  for (int o = 16; o > 0; o >>= 1) x += __shfl_xor(x, o, 32);
  return x;
}

// deg (float, counts both endpoints) + hist (int, counts row occurrences)
__global__ void k_deg(const int* __restrict__ ei, float* __restrict__ deg,
                      int* __restrict__ hist) {
  int e = blockIdx.x * 256 + threadIdx.x;
  if (e < EE) {
    int r = ei[e];
    atomicAdd(deg + r, 1.0f);
    atomicAdd(deg + ei[EE + e], 1.0f);
    atomicAdd(hist + r, 1);
  }
}

// single-block exclusive scan over hist[NN] -> row_start[NN+1], cursor[NN]
__global__ __launch_bounds__(1024) void k_scan(const int* __restrict__ hist,
                                               int* __restrict__ row_start,
                                               int* __restrict__ cursor) {
  __shared__ int part[1024];
  const int t = threadIdx.x;
  const int base = t * 40;              // 1024*40 >= NN
  int s = 0;
  for (int i = base; i < base + 40 && i < NN; ++i) s += hist[i];
  part[t] = s;
  __syncthreads();
  for (int off = 1; off < 1024; off <<= 1) {
    int v = (t >= off) ? part[t - off] : 0;
    __syncthreads();
    part[t] += v;
    __syncthreads();
  }
  int ex = (t == 0) ? 0 : part[t - 1];
  for (int i = base; i < base + 40 && i < NN; ++i) {
    row_start[i] = ex;
    cursor[i] = ex;
    ex += hist[i];
  }
  if (t == 0) row_start[NN] = EE;
}

// v0 = N(0,1) via exact JAX threefry pipeline; normalization deferred (scale-free).
__global__ void k_genv(float* __restrict__ v) {
  int i = blockIdx.x * 256 + threadIdx.x;  // exact ND
  unsigned o0, o1;
  threefry2x32(0u, 42u, 0u, (unsigned)i, o0, o1);
  unsigned bits = o1;
  float f = __uint_as_float((bits >> 9) | 0x3f800000u) - 1.0f;  // [0,1)
  const float lo = -0.99999994f;                                 // nextafter(-1,0)
  float u = fmaxf(lo, f * 2.0f + lo);
  v[i] = 1.41421354f * erfinvf(u);
}

__device__ __forceinline__ int clamp8(float q) {
  int v = (int)rintf(q);
  return v < -127 ? -127 : (v > 127 ? 127 : v);
}
__device__ __forceinline__ unsigned pack4v(fv4 q, float inv) {
  int q0 = clamp8(q.x * inv), q1 = clamp8(q.y * inv),
      q2 = clamp8(q.z * inv), q3 = clamp8(q.w * inv);
  return (q0 & 255) | ((q1 & 255) << 8) | ((q2 & 255) << 16) | ((q3 & 255) << 24);
}
__device__ __forceinline__ void dp4(unsigned u, fv4 xv, float& acc) {
  acc = fmaf((float)(signed char)(u),        xv.x, acc);
  acc = fmaf((float)(signed char)(u >> 8),   xv.y, acc);
  acc = fmaf((float)(signed char)(u >> 16),  xv.z, acc);
  acc = fmaf((float)(signed char)(u >> 24),  xv.w, acc);
}

// Convert Q -> int8 (per-row fp16 scale), writing into row-sorted CSR position.
__global__ __launch_bounds__(256) void k_cvt(const float* __restrict__ Q,
                                             const int* __restrict__ ei,
                                             int* __restrict__ cursor,
                                             char* __restrict__ Qi8,
                                             __half* __restrict__ Qs,
                                             int* __restrict__ cols) {
  const int slot = threadIdx.x >> 5;
  const int lane = threadIdx.x & 31;
  const int e = blockIdx.x * 8 + slot;  // EE % 8 == 0
  const int row = ei[e];
  const int col = ei[EE + e];
  int pos = 0;
  if (lane == 0) pos = atomicAdd(cursor + row, 1);
  pos = __shfl(pos, 0, 32);
  const fv4* __restrict__ q4 =
      (const fv4*)(Q + (size_t)e * (DD * DD) + (size_t)lane * DD);
  fv4 qf[8];
#pragma unroll
  for (int k = 0; k < 8; ++k) qf[k] = __builtin_nontemporal_load(q4 + k);
  float m = 0.0f;
#pragma unroll
  for (int k = 0; k < 8; ++k) {
    m = fmaxf(m, fmaxf(fmaxf(fabsf(qf[k].x), fabsf(qf[k].y)),
                       fmaxf(fabsf(qf[k].z), fabsf(qf[k].w))));
  }
  __half sh = __float2half(m * (1.0f / 127.0f));
  float s = __half2float(sh);
  float inv = (s > 0.0f) ? 1.0f / s : 0.0f;
  uv4 pa, pb;
  pa.x = pack4v(qf[0], inv); pa.y = pack4v(qf[1], inv);
  pa.z = pack4v(qf[2], inv); pa.w = pack4v(qf[3], inv);
  pb.x = pack4v(qf[4], inv); pb.y = pack4v(qf[5], inv);
  pb.z = pack4v(qf[6], inv); pb.w = pack4v(qf[7], inv);
  uv4* __restrict__ qs = (uv4*)(Qi8 + (size_t)pos * (DD * DD) + (size_t)lane * DD);
  qs[0] = pa;   // cached stores: sorted Q copy (218 MB) targets L3 residency
  qs[1] = pb;
  Qs[pos * DD + lane] = sh;
  if (lane == 0) cols[pos] = col;
}

// Gather matvec, one wave64 per row, 2 edges per iteration.
// lanes 0-31: edge p (dims 0-31); lanes 32-63: edge p+1 (same dims).
// Final combine: acc += shfl_xor(acc, 32). Cols preloaded into lane registers.
// mode 0: out = deg*x - off
// mode 1: out = alpha*(deg*x - off) - x
// mode 2: out = 2*alpha*(deg*x - off) - 2x - xprev
__global__ __launch_bounds__(256) void k_gather(const float* __restrict__ x,
                                                const float* __restrict__ xprev,
                                                const char* __restrict__ Qi8,
                                                const __half* __restrict__ Qs,
                                                const int* __restrict__ cols,
                                                const int* __restrict__ row_start,
                                                const float* __restrict__ deg,
                                                const float* __restrict__ scal,
                                                float* __restrict__ out, int mode) {
  const int wid  = threadIdx.x >> 6;     // 4 waves per block
  const int lane = threadIdx.x & 63;
  const int half = lane >> 5;            // 0: edge p, 1: edge p+1
  const int d    = lane & 31;            // output dim
  const int r = blockIdx.x * 4 + wid;    // NN % 4 == 0
  const int beg = row_start[r];
  const int end = row_start[r + 1];
  const int degree = end - beg;

  float acc = 0.0f;
  for (int chunk = 0; chunk < degree; chunk += 64) {
    const int nchunk = min(64, degree - chunk);
    // coalesced preload of this chunk's cols into lane registers
    int myc = (lane < nchunk) ? cols[beg + chunk + lane] : 0;
    for (int p0 = 0; p0 < nchunk; p0 += 2) {
      const int p = p0 + half;
      const bool act = p < nchunk;
      const int col = __shfl(myc, p, 64);       // register broadcast, no mem dep
      const int pos = beg + chunk + p;
      if (act) {
        const fv4* __restrict__ x4 = (const fv4*)(x + (size_t)col * DD);
        fv4 xr[8];
#pragma unroll
        for (int k = 0; k < 8; ++k) xr[k] = x4[k];
        const uv4* __restrict__ q8 =
            (const uv4*)(Qi8 + (size_t)pos * (DD * DD) + (size_t)d * DD);
        uv4 pa = q8[0];
        uv4 pb = q8[1];
        float s = __half2float(Qs[pos * DD + d]);
        float dot = 0.0f;
        dp4(pa.x, xr[0], dot); dp4(pa.y, xr[1], dot);
        dp4(pa.z, xr[2], dot); dp4(pa.w, xr[3], dot);
        dp4(pb.x, xr[4], dot); dp4(pb.y, xr[5], dot);
        dp4(pb.z, xr[6], dot); dp4(pb.w, xr[7], dot);
        acc = fmaf(s, dot, acc);
      }
    }
  }
  acc += __shfl_xor(acc, 32, 64);  // combine the two edge-halves per dim

  if (half == 0) {
    const size_t idx = (size_t)r * DD + d;
    const float xi = x[idx];
    const float dv = deg[r];
    float o;
    if (mode == 0)      o = dv * xi - acc;
    else if (mode == 1) o = scal[SLOT_ALPHA] * (dv * xi - acc) - xi;
    else                o = 2.0f * scal[SLOT_ALPHA] * (dv * xi - acc)
                            - 2.0f * xi - xprev[idx];
    out[idx] = o;
  }
}

// f32 fallback matvec pieces (only if ws_size too small for the CSR copy)
__global__ void k_pre(const float* __restrict__ x, const float* __restrict__ xprev,
                      const float* __restrict__ deg, const float* __restrict__ scal,
                      float* __restrict__ out, int mode) {
  int i = blockIdx.x * 256 + threadIdx.x;
  float d = deg[i >> 5];
  float xi = x[i];
  if (mode == 0)       out[i] = d * xi;
  else if (mode == 1)  out[i] = scal[SLOT_ALPHA] * d * xi - xi;
  else                 out[i] = 2.0f * scal[SLOT_ALPHA] * d * xi - 2.0f * xi - xprev[i];
}

__global__ __launch_bounds__(256) void k_matvec(const float* __restrict__ x,
                                                const float* __restrict__ Q,
                                                const int* __restrict__ ei,
                                                float* __restrict__ out,
                                                const float* __restrict__ scal,
                                                int use_alpha, float smul) {
  const int slot = threadIdx.x >> 5;
  const int lane = threadIdx.x & 31;
  const int e = blockIdx.x * 8 + slot;
  const float factor = use_alpha ? scal[SLOT_ALPHA] * smul : smul;
  const int row = ei[e];
  const int col = ei[EE + e];
  const fv4* __restrict__ x4 = (const fv4*)(x + (size_t)col * DD);
  fv4 xr[8];
#pragma unroll
  for (int k = 0; k < 8; ++k) xr[k] = x4[k];
  const fv4* __restrict__ q4 =
      (const fv4*)(Q + (size_t)e * (DD * DD) + (size_t)lane * DD);
  float acc = 0.0f;
#pragma unroll
  for (int k = 0; k < 8; ++k) {
    fv4 q = q4[k];
    acc = fmaf(q.x, xr[k].x, acc);
    acc = fmaf(q.y, xr[k].y, acc);
    acc = fmaf(q.z, xr[k].z, acc);
    acc = fmaf(q.w, xr[k].w, acc);
  }
  atomicAdd(out + (size_t)row * DD + lane, -factor * acc);
}

#define DOT_BLOCKS 640
__global__ void k_dots(const float* __restrict__ u4, const float* __restrict__ u5,
                       float* __restrict__ scal) {
  float s1 = 0.0f, s2 = 0.0f;
  for (int i = blockIdx.x * 256 + threadIdx.x; i < ND; i += DOT_BLOCKS * 256) {
    float a = u4[i], b = u5[i];
    s1 = fmaf(a, b, s1);
    s2 = fmaf(a, a, s2);
  }
  s1 = wave64_sum(s1);
  s2 = wave64_sum(s2);
  __shared__ float ls1[4], ls2[4];
  int w = threadIdx.x >> 6;
  if ((threadIdx.x & 63) == 0) { ls1[w] = s1; ls2[w] = s2; }
  __syncthreads();
  if (threadIdx.x == 0) {
    atomicAdd(scal + SLOT_S1, ls1[0] + ls1[1] + ls1[2] + ls1[3]);
    atomicAdd(scal + SLOT_S2, ls2[0] + ls2[1] + ls2[2] + ls2[3]);
  }
}

__global__ void k_alpha(float* __restrict__ scal) {
  float lam = scal[SLOT_S1] / scal[SLOT_S2] / (1.0f + 1e-8f);
  lam = fmaxf(lam, 1.0f);
  scal[SLOT_ALPHA] = 2.0f / (lam + 1e-8f);
}

__global__ __launch_bounds__(256) void k_fuse(
    const float* __restrict__ h,
    const float* __restrict__ T1, const float* __restrict__ T2,
    const float* __restrict__ T3, const float* __restrict__ T4,
    const float* __restrict__ coeffs,
    const float* __restrict__ projW, const float* __restrict__ projb,
    const float* __restrict__ projg, const float* __restrict__ projbeta,
    const float* __restrict__ fusW1, const float* __restrict__ fusb1,
    const float* __restrict__ fusg, const float* __restrict__ fusbeta,
    const float* __restrict__ fusW2, const float* __restrict__ fusb2,
    float* __restrict__ out) {
  __shared__ float s_res[8][3][DD];
  __shared__ float s_p[8][3 * DD];
  __shared__ float s_s[8][DD];
  const int slot = threadIdx.x >> 5;
  const int lane = threadIdx.x & 31;
  const int n = blockIdx.x * 8 + slot;  // 5000 blocks exact

  float w[3][5];
#pragma unroll
  for (int b = 0; b < 3; ++b) {
    float m = -1e30f;
#pragma unroll
    for (int k = 0; k < 5; ++k) m = fmaxf(m, coeffs[b * 5 + k]);
    float s = 0.0f;
#pragma unroll
    for (int k = 0; k < 5; ++k) { w[b][k] = expf(coeffs[b * 5 + k] - m); s += w[b][k]; }
#pragma unroll
    for (int k = 0; k < 5; ++k) w[b][k] /= s;
  }

  const int idx = n * DD + lane;
  float hd = h[idx], t1 = T1[idx], t2 = T2[idx], t3 = T3[idx], t4 = T4[idx];
#pragma unroll
  for (int b = 0; b < 3; ++b)
    s_res[slot][b][lane] =
        w[b][0] * hd + w[b][1] * t1 + w[b][2] * t2 + w[b][3] * t3 + w[b][4] * t4;
  __syncthreads();

#pragma unroll
  for (int b = 0; b < 3; ++b) {
    float y = projb[b * DD + lane];
#pragma unroll
    for (int j = 0; j < DD; ++j)
      y = fmaf(s_res[slot][b][j], projW[(b * DD + j) * DD + lane], y);
    float mu = g32_sum(y) * (1.0f / DD);
    float d = y - mu;
    float var = g32_sum(d * d) * (1.0f / DD);
    float z = d * rsqrtf(var + LNEPS) * projg[b * DD + lane] + projbeta[b * DD + lane];
    float pb = z / (1.0f + expf(-z));  // silu
    s_p[slot][b * DD + lane] = pb;
  }
  __syncthreads();

  float y = fusb1[lane];
#pragma unroll
  for (int j = 0; j < 3 * DD; ++j)
    y = fmaf(s_p[slot][j], fusW1[j * DD + lane], y);
  float mu = g32_sum(y) * (1.0f / DD);
  float d = y - mu;
  float var = g32_sum(d * d) * (1.0f / DD);
  float z = d * rsqrtf(var + LNEPS) * fusg[lane] + fusbeta[lane];
  float sv = z / (1.0f + expf(-z));
  s_s[slot][lane] = sv;
  __syncthreads();

  float o = fusb2[lane];
#pragma unroll
  for (int j = 0; j < DD; ++j)
    o = fmaf(s_s[slot][j], fusW2[j * DD + lane], o);
  out[idx] = hd + o;
}

extern "C" void kernel_launch(void* const* d_in, const int* in_sizes, int n_in,
                              void* d_out, int out_size, void* d_ws, size_t ws_size,
                              hipStream_t stream) {
  (void)in_sizes; (void)n_in; (void)out_size;
  const float* h        = (const float*)d_in[0];
  const float* Q        = (const float*)d_in[1];
  const int*   ei       = (const int*)d_in[2];
  const float* coeffs   = (const float*)d_in[3];
  const float* projW    = (const float*)d_in[4];
  const float* projb    = (const float*)d_in[5];
  const float* projg    = (const float*)d_in[6];
  const float* projbeta = (const float*)d_in[7];
  const float* fusW1    = (const float*)d_in[8];
  const float* fusb1    = (const float*)d_in[9];
  const float* fusg     = (const float*)d_in[10];
  const float* fusbeta  = (const float*)d_in[11];
  const float* fusW2    = (const float*)d_in[12];
  const float* fusb2    = (const float*)d_in[13];
  float* out = (float*)d_out;

  // workspace layout
  const size_t qi_bytes  = (size_t)EE * DD * DD;              // 204.8 MB
  const size_t qs_bytes  = (size_t)EE * DD * sizeof(__half);  // 12.8 MB
  const size_t col_bytes = (size_t)EE * sizeof(int);          // 0.8 MB
  const size_t idx_bytes = (size_t)(3 * NN + 2) * sizeof(int);
  const size_t f32_elems = 6u * (size_t)ND + NN + 64;
  const size_t need = qi_bytes + qs_bytes + col_bytes + idx_bytes +
                      f32_elems * sizeof(float) + 256;
  const bool fast = ws_size >= need;

  char*   Qi8 = (char*)d_ws;
  __half* Qs  = (__half*)((char*)d_ws + qi_bytes);
  int*  cols      = (int*)((char*)d_ws + qi_bytes + qs_bytes);
  int*  row_start = cols + EE;            // NN+1
  int*  cursor    = row_start + NN + 1;   // NN
  float* base = fast
      ? (float*)((char*)d_ws + ((qi_bytes + qs_bytes + col_bytes + idx_bytes + 255) & ~(size_t)255))
      : (float*)d_ws;
  float* uA   = base;             // [ND]
  float* uB   = uA + ND;          // [ND]
  float* T1   = uB + ND;          // [ND]
  float* T2   = T1 + ND;          // [ND]
  float* T3   = T2 + ND;          // [ND]
  float* T4   = T3 + ND;          // [ND]
  float* deg  = T4 + ND;          // [NN]
  float* scal = deg + NN;         // [64]
  int*   hist = (int*)(scal + 64);  // [NN] — zeroed together with deg/scal

  (void)hipMemsetAsync(deg, 0, (2 * NN + 64) * sizeof(float), stream);

  k_deg<<<(EE + 255) / 256, 256, 0, stream>>>(ei, deg, hist);
  k_genv<<<ND / 256, 256, 0, stream>>>(uA);

  if (fast) {
    k_scan<<<1, 1024, 0, stream>>>(hist, row_start, cursor);
    k_cvt<<<EE / 8, 256, 0, stream>>>(Q, ei, cursor, Qi8, Qs, cols);

    // power iteration, unnormalized: u_{k+1} = L u_k
    float* cur = uA;
    float* nxt = uB;
    for (int it = 0; it < 5; ++it) {
      k_gather<<<NN / 4, 256, 0, stream>>>(cur, nullptr, Qi8, Qs, cols,
                                           row_start, deg, scal, nxt, 0);
      float* t = cur; cur = nxt; nxt = t;
    }
    k_dots<<<DOT_BLOCKS, 256, 0, stream>>>(nxt, cur, scal);
    k_alpha<<<1, 1, 0, stream>>>(scal);

    // Chebyshev: T1 = alpha*L h - h ; T_next = 2*(alpha*L x - x) - xprev
    const float* xin[4]   = {h, T1, T2, T3};
    const float* prevs[4] = {nullptr, h, T1, T2};
    float* touts[4]       = {T1, T2, T3, T4};
    for (int k = 0; k < 4; ++k) {
      k_gather<<<NN / 4, 256, 0, stream>>>(xin[k], prevs[k], Qi8, Qs, cols,
                                           row_start, deg, scal, touts[k],
                                           k == 0 ? 1 : 2);
    }
  } else {
    // f32 atomic-scatter fallback
    float* cur = uA;
    float* nxt = uB;
    for (int it = 0; it < 5; ++it) {
      k_pre<<<ND / 256, 256, 0, stream>>>(cur, nullptr, deg, scal, nxt, 0);
      k_matvec<<<EE / 8, 256, 0, stream>>>(cur, Q, ei, nxt, scal, 0, 1.0f);
      float* t = cur; cur = nxt; nxt = t;
    }
    k_dots<<<DOT_BLOCKS, 256, 0, stream>>>(nxt, cur, scal);
    k_alpha<<<1, 1, 0, stream>>>(scal);
    const float* xin[4]   = {h, T1, T2, T3};
    const float* prevs[4] = {nullptr, h, T1, T2};
    float* touts[4]       = {T1, T2, T3, T4};
    for (int k = 0; k < 4; ++k) {
      k_pre<<<ND / 256, 256, 0, stream>>>(xin[k], prevs[k], deg, scal, touts[k],
                                          k == 0 ? 1 : 2);
      k_matvec<<<EE / 8, 256, 0, stream>>>(xin[k], Q, ei, touts[k], scal, 1,
                                           k == 0 ? 1.0f : 2.0f);
    }
  }

  k_fuse<<<NN / 8, 256, 0, stream>>>(h, T1, T2, T3, T4, coeffs,
                                     projW, projb, projg, projbeta,
                                     fusW1, fusb1, fusg, fusbeta,
                                     fusW2, fusb2, out);
}

// Round 8
// 950.865 us; speedup vs baseline: 6.2951x; 1.0347x over previous
//
#include <hip/hip_runtime.h>
#include <hip/hip_fp16.h>
#include <math.h>

#define NN 40000
#define EE 200000
#define DD 32
#define ND (NN * DD)        // 1,280,000
#define LNEPS 1e-5f

typedef float    fv4 __attribute__((ext_vector_type(4)));
typedef unsigned uv4 __attribute__((ext_vector_type(4)));

// scal slots — separate cache lines for atomically-updated slots
#define SLOT_S1    0    // u4 . u5
#define SLOT_S2    32   // u4 . u4
#define SLOT_ALPHA 48   // 2 / (lam + eps)

__device__ __forceinline__ void threefry2x32(unsigned k0, unsigned k1,
                                             unsigned x0, unsigned x1,
                                             unsigned& o0, unsigned& o1) {
  const unsigned k2 = k0 ^ k1 ^ 0x1BD11BDAu;
  unsigned v0 = x0 + k0, v1 = x1 + k1;
#define TF_ROUND(r) { v0 += v1; v1 = (v1 << (r)) | (v1 >> (32 - (r))); v1 ^= v0; }
  TF_ROUND(13) TF_ROUND(15) TF_ROUND(26) TF_ROUND(6)
  v0 += k1; v1 += k2 + 1u;
  TF_ROUND(17) TF_ROUND(29) TF_ROUND(16) TF_ROUND(24)
  v0 += k2; v1 += k0 + 2u;
  TF_ROUND(13) TF_ROUND(15) TF_ROUND(26) TF_ROUND(6)
  v0 += k0; v1 += k1 + 3u;
  TF_ROUND(17) TF_ROUND(29) TF_ROUND(16) TF_ROUND(24)
  v0 += k1; v1 += k2 + 4u;
  TF_ROUND(13) TF_ROUND(15) TF_ROUND(26) TF_ROUND(6)
  v0 += k2; v1 += k0 + 5u;
#undef TF_ROUND
  o0 = v0; o1 = v1;
}

__device__ __forceinline__ float wave64_sum(float x) {
  for (int o = 32; o > 0; o >>= 1) x += __shfl_xor(x, o, 64);
  return x;
}
__device__ __forceinline__ float g32_sum(float x) {
  for (int o = 16; o > 0; o >>= 1) x += __shfl_xor(x, o, 32);
  return x;
}

// deg (float, counts both endpoints) + hist (int, counts row occurrences)
__global__ void k_deg(const int* __restrict__ ei, float* __restrict__ deg,
                      int* __restrict__ hist) {
  int e = blockIdx.x * 256 + threadIdx.x;
  if (e < EE) {
    int r = ei[e];
    atomicAdd(deg + r, 1.0f);
    atomicAdd(deg + ei[EE + e], 1.0f);
    atomicAdd(hist + r, 1);
  }
}

// single-block exclusive scan over hist[NN] -> row_start[NN+1], cursor[NN]
__global__ __launch_bounds__(1024) void k_scan(const int* __restrict__ hist,
                                               int* __restrict__ row_start,
                                               int* __restrict__ cursor) {
  __shared__ int part[1024];
  const int t = threadIdx.x;
  const int base = t * 40;              // 1024*40 >= NN
  int s = 0;
  for (int i = base; i < base + 40 && i < NN; ++i) s += hist[i];
  part[t] = s;
  __syncthreads();
  for (int off = 1; off < 1024; off <<= 1) {
    int v = (t >= off) ? part[t - off] : 0;
    __syncthreads();
    part[t] += v;
    __syncthreads();
  }
  int ex = (t == 0) ? 0 : part[t - 1];
  for (int i = base; i < base + 40 && i < NN; ++i) {
    row_start[i] = ex;
    cursor[i] = ex;
    ex += hist[i];
  }
  if (t == 0) row_start[NN] = EE;
}

// v0 = N(0,1) via exact JAX threefry pipeline; normalization deferred (scale-free).
__global__ void k_genv(float* __restrict__ v) {
  int i = blockIdx.x * 256 + threadIdx.x;  // exact ND
  unsigned o0, o1;
  threefry2x32(0u, 42u, 0u, (unsigned)i, o0, o1);
  unsigned bits = o1;
  float f = __uint_as_float((bits >> 9) | 0x3f800000u) - 1.0f;  // [0,1)
  const float lo = -0.99999994f;                                 // nextafter(-1,0)
  float u = fmaxf(lo, f * 2.0f + lo);
  v[i] = 1.41421354f * erfinvf(u);
}

__device__ __forceinline__ int clamp8(float q) {
  int v = (int)rintf(q);
  return v < -127 ? -127 : (v > 127 ? 127 : v);
}
__device__ __forceinline__ unsigned pack4v(fv4 q, float inv) {
  int q0 = clamp8(q.x * inv), q1 = clamp8(q.y * inv),
      q2 = clamp8(q.z * inv), q3 = clamp8(q.w * inv);
  return (q0 & 255) | ((q1 & 255) << 8) | ((q2 & 255) << 16) | ((q3 & 255) << 24);
}
__device__ __forceinline__ void dp4(unsigned u, fv4 xv, float& acc) {
  acc = fmaf((float)(signed char)(u),        xv.x, acc);
  acc = fmaf((float)(signed char)(u >> 8),   xv.y, acc);
  acc = fmaf((float)(signed char)(u >> 16),  xv.z, acc);
  acc = fmaf((float)(signed char)(u >> 24),  xv.w, acc);
}

// Convert Q -> int8 (per-row fp16 scale), writing into row-sorted CSR position.
__global__ __launch_bounds__(256) void k_cvt(const float* __restrict__ Q,
                                             const int* __restrict__ ei,
                                             int* __restrict__ cursor,
                                             char* __restrict__ Qi8,
                                             __half* __restrict__ Qs,
                                             int* __restrict__ cols) {
  const int slot = threadIdx.x >> 5;
  const int lane = threadIdx.x & 31;
  const int e = blockIdx.x * 8 + slot;  // EE % 8 == 0
  const int row = ei[e];
  const int col = ei[EE + e];
  int pos = 0;
  if (lane == 0) pos = atomicAdd(cursor + row, 1);
  pos = __shfl(pos, 0, 32);
  const fv4* __restrict__ q4 =
      (const fv4*)(Q + (size_t)e * (DD * DD) + (size_t)lane * DD);
  fv4 qf[8];
#pragma unroll
  for (int k = 0; k < 8; ++k) qf[k] = __builtin_nontemporal_load(q4 + k);
  float m = 0.0f;
#pragma unroll
  for (int k = 0; k < 8; ++k) {
    m = fmaxf(m, fmaxf(fmaxf(fabsf(qf[k].x), fabsf(qf[k].y)),
                       fmaxf(fabsf(qf[k].z), fabsf(qf[k].w))));
  }
  __half sh = __float2half(m * (1.0f / 127.0f));
  float s = __half2float(sh);
  float inv = (s > 0.0f) ? 1.0f / s : 0.0f;
  uv4 pa, pb;
  pa.x = pack4v(qf[0], inv); pa.y = pack4v(qf[1], inv);
  pa.z = pack4v(qf[2], inv); pa.w = pack4v(qf[3], inv);
  pb.x = pack4v(qf[4], inv); pb.y = pack4v(qf[5], inv);
  pb.z = pack4v(qf[6], inv); pb.w = pack4v(qf[7], inv);
  uv4* __restrict__ qs = (uv4*)(Qi8 + (size_t)pos * (DD * DD) + (size_t)lane * DD);
  qs[0] = pa;   // cached stores: sorted Q copy (218 MB) targets L3 residency
  qs[1] = pb;
  Qs[pos * DD + lane] = sh;
  if (lane == 0) cols[pos] = col;
}

#define CHUNK 16

// Gather matvec, one wave64 per row.
// Per 16-edge chunk: stage all neighbor x-rows into LDS in ONE parallel
// round trip (lane l stages 8 floats of edge l>>2), then the dot loop
// reads x via same-address LDS broadcasts. Q loads rotate 1 pair ahead.
// lanes 0-31: edge p (dims 0-31); lanes 32-63: edge p+1 (same dims);
// combine via shfl_xor(acc,32). Accumulation order per lane identical
// to r7 (bit-exact).
// mode 0: out = deg*x - off
// mode 1: out = alpha*(deg*x - off) - x
// mode 2: out = 2*alpha*(deg*x - off) - 2x - xprev
__global__ __launch_bounds__(256) void k_gather(const float* __restrict__ x,
                                                const float* __restrict__ xprev,
                                                const char* __restrict__ Qi8,
                                                const __half* __restrict__ Qs,
                                                const int* __restrict__ cols,
                                                const int* __restrict__ row_start,
                                                const float* __restrict__ deg,
                                                const float* __restrict__ scal,
                                                float* __restrict__ out, int mode) {
  __shared__ float lds[4][CHUNK][DD];    // 8 KB
  const int wid  = threadIdx.x >> 6;     // 4 waves per block
  const int lane = threadIdx.x & 63;
  const int half = lane >> 5;            // 0: edge p, 1: edge p+1
  const int d    = lane & 31;            // output dim
  const int r = blockIdx.x * 4 + wid;    // NN % 4 == 0
  const int beg = row_start[r];
  const int end = row_start[r + 1];
  const int degree = end - beg;

  float acc = 0.0f;
  for (int chunk = 0; chunk < degree; chunk += CHUNK) {
    const int nchunk = min(CHUNK, degree - chunk);
    // chunk cols into lane registers (coalesced, lanes 0..nchunk-1)
    int myc = (lane < nchunk) ? cols[beg + chunk + lane] : 0;
    // stage x rows: lane l covers edge el=l>>2, floats (l&3)*8 .. +7
    {
      const int el = lane >> 2;
      const int pt = lane & 3;
      if (el < nchunk) {
        const int c = __shfl(myc, el, 64);
        const fv4* __restrict__ xs = (const fv4*)(x + (size_t)c * DD);
        fv4 a = xs[pt * 2];
        fv4 b = xs[pt * 2 + 1];
        fv4* __restrict__ dst = (fv4*)&lds[wid][el][pt * 8];
        dst[0] = a;
        dst[1] = b;
      }
    }
    // compute, Q prefetched one pair ahead
    uv4 qa = {0, 0, 0, 0}, qb = {0, 0, 0, 0};
    float sc = 0.0f;
    {
      const int p = half;
      if (p < nchunk) {
        const size_t pos = (size_t)(beg + chunk + p);
        const uv4* __restrict__ q8 = (const uv4*)(Qi8 + pos * (DD * DD) + (size_t)d * DD);
        qa = q8[0];
        qb = q8[1];
        sc = __half2float(Qs[pos * DD + d]);
      }
    }
    for (int p0 = 0; p0 < nchunk; p0 += 2) {
      const int pn = p0 + 2 + half;
      uv4 na = {0, 0, 0, 0}, nb = {0, 0, 0, 0};
      float ns = 0.0f;
      if (pn < nchunk) {
        const size_t pos = (size_t)(beg + chunk + pn);
        const uv4* __restrict__ q8 = (const uv4*)(Qi8 + pos * (DD * DD) + (size_t)d * DD);
        na = q8[0];
        nb = q8[1];
        ns = __half2float(Qs[pos * DD + d]);
      }
      const int p = p0 + half;
      if (p < nchunk) {
        const fv4* __restrict__ xl = (const fv4*)&lds[wid][p][0];
        fv4 xr[8];
#pragma unroll
        for (int k = 0; k < 8; ++k) xr[k] = xl[k];
        float dot = 0.0f;
        dp4(qa.x, xr[0], dot); dp4(qa.y, xr[1], dot);
        dp4(qa.z, xr[2], dot); dp4(qa.w, xr[3], dot);
        dp4(qb.x, xr[4], dot); dp4(qb.y, xr[5], dot);
        dp4(qb.z, xr[6], dot); dp4(qb.w, xr[7], dot);
        acc = fmaf(sc, dot, acc);
      }
      qa = na; qb = nb; sc = ns;
    }
  }
  acc += __shfl_xor(acc, 32, 64);  // combine the two edge-halves per dim

  if (half == 0) {
    const size_t idx = (size_t)r * DD + d;
    const float xi = x[idx];
    const float dv = deg[r];
    float o;
    if (mode == 0)      o = dv * xi - acc;
    else if (mode == 1) o = scal[SLOT_ALPHA] * (dv * xi - acc) - xi;
    else                o = 2.0f * scal[SLOT_ALPHA] * (dv * xi - acc)
                            - 2.0f * xi - xprev[idx];
    out[idx] = o;
  }
}

// f32 fallback matvec pieces (only if ws_size too small for the CSR copy)
__global__ void k_pre(const float* __restrict__ x, const float* __restrict__ xprev,
                      const float* __restrict__ deg, const float* __restrict__ scal,
                      float* __restrict__ out, int mode) {
  int i = blockIdx.x * 256 + threadIdx.x;
  float d = deg[i >> 5];
  float xi = x[i];
  if (mode == 0)       out[i] = d * xi;
  else if (mode == 1)  out[i] = scal[SLOT_ALPHA] * d * xi - xi;
  else                 out[i] = 2.0f * scal[SLOT_ALPHA] * d * xi - 2.0f * xi - xprev[i];
}

__global__ __launch_bounds__(256) void k_matvec(const float* __restrict__ x,
                                                const float* __restrict__ Q,
                                                const int* __restrict__ ei,
                                                float* __restrict__ out,
                                                const float* __restrict__ scal,
                                                int use_alpha, float smul) {
  const int slot = threadIdx.x >> 5;
  const int lane = threadIdx.x & 31;
  const int e = blockIdx.x * 8 + slot;
  const float factor = use_alpha ? scal[SLOT_ALPHA] * smul : smul;
  const int row = ei[e];
  const int col = ei[EE + e];
  const fv4* __restrict__ x4 = (const fv4*)(x + (size_t)col * DD);
  fv4 xr[8];
#pragma unroll
  for (int k = 0; k < 8; ++k) xr[k] = x4[k];
  const fv4* __restrict__ q4 =
      (const fv4*)(Q + (size_t)e * (DD * DD) + (size_t)lane * DD);
  float acc = 0.0f;
#pragma unroll
  for (int k = 0; k < 8; ++k) {
    fv4 q = q4[k];
    acc = fmaf(q.x, xr[k].x, acc);
    acc = fmaf(q.y, xr[k].y, acc);
    acc = fmaf(q.z, xr[k].z, acc);
    acc = fmaf(q.w, xr[k].w, acc);
  }
  atomicAdd(out + (size_t)row * DD + lane, -factor * acc);
}

#define DOT_BLOCKS 640
__global__ void k_dots(const float* __restrict__ u4, const float* __restrict__ u5,
                       float* __restrict__ scal) {
  float s1 = 0.0f, s2 = 0.0f;
  for (int i = blockIdx.x * 256 + threadIdx.x; i < ND; i += DOT_BLOCKS * 256) {
    float a = u4[i], b = u5[i];
    s1 = fmaf(a, b, s1);
    s2 = fmaf(a, a, s2);
  }
  s1 = wave64_sum(s1);
  s2 = wave64_sum(s2);
  __shared__ float ls1[4], ls2[4];
  int w = threadIdx.x >> 6;
  if ((threadIdx.x & 63) == 0) { ls1[w] = s1; ls2[w] = s2; }
  __syncthreads();
  if (threadIdx.x == 0) {
    atomicAdd(scal + SLOT_S1, ls1[0] + ls1[1] + ls1[2] + ls1[3]);
    atomicAdd(scal + SLOT_S2, ls2[0] + ls2[1] + ls2[2] + ls2[3]);
  }
}

__global__ void k_alpha(float* __restrict__ scal) {
  float lam = scal[SLOT_S1] / scal[SLOT_S2] / (1.0f + 1e-8f);
  lam = fmaxf(lam, 1.0f);
  scal[SLOT_ALPHA] = 2.0f / (lam + 1e-8f);
}

__global__ __launch_bounds__(256) void k_fuse(
    const float* __restrict__ h,
    const float* __restrict__ T1, const float* __restrict__ T2,
    const float* __restrict__ T3, const float* __restrict__ T4,
    const float* __restrict__ coeffs,
    const float* __restrict__ projW, const float* __restrict__ projb,
    const float* __restrict__ projg, const float* __restrict__ projbeta,
    const float* __restrict__ fusW1, const float* __restrict__ fusb1,
    const float* __restrict__ fusg, const float* __restrict__ fusbeta,
    const float* __restrict__ fusW2, const float* __restrict__ fusb2,
    float* __restrict__ out) {
  __shared__ float s_res[8][3][DD];
  __shared__ float s_p[8][3 * DD];
  __shared__ float s_s[8][DD];
  const int slot = threadIdx.x >> 5;
  const int lane = threadIdx.x & 31;
  const int n = blockIdx.x * 8 + slot;  // 5000 blocks exact

  float w[3][5];
#pragma unroll
  for (int b = 0; b < 3; ++b) {
    float m = -1e30f;
#pragma unroll
    for (int k = 0; k < 5; ++k) m = fmaxf(m, coeffs[b * 5 + k]);
    float s = 0.0f;
#pragma unroll
    for (int k = 0; k < 5; ++k) { w[b][k] = expf(coeffs[b * 5 + k] - m); s += w[b][k]; }
#pragma unroll
    for (int k = 0; k < 5; ++k) w[b][k] /= s;
  }

  const int idx = n * DD + lane;
  float hd = h[idx], t1 = T1[idx], t2 = T2[idx], t3 = T3[idx], t4 = T4[idx];
#pragma unroll
  for (int b = 0; b < 3; ++b)
    s_res[slot][b][lane] =
        w[b][0] * hd + w[b][1] * t1 + w[b][2] * t2 + w[b][3] * t3 + w[b][4] * t4;
  __syncthreads();

#pragma unroll
  for (int b = 0; b < 3; ++b) {
    float y = projb[b * DD + lane];
#pragma unroll
    for (int j = 0; j < DD; ++j)
      y = fmaf(s_res[slot][b][j], projW[(b * DD + j) * DD + lane], y);
    float mu = g32_sum(y) * (1.0f / DD);
    float d = y - mu;
    float var = g32_sum(d * d) * (1.0f / DD);
    float z = d * rsqrtf(var + LNEPS) * projg[b * DD + lane] + projbeta[b * DD + lane];
    float pb = z / (1.0f + expf(-z));  // silu
    s_p[slot][b * DD + lane] = pb;
  }
  __syncthreads();

  float y = fusb1[lane];
#pragma unroll
  for (int j = 0; j < 3 * DD; ++j)
    y = fmaf(s_p[slot][j], fusW1[j * DD + lane], y);
  float mu = g32_sum(y) * (1.0f / DD);
  float d = y - mu;
  float var = g32_sum(d * d) * (1.0f / DD);
  float z = d * rsqrtf(var + LNEPS) * fusg[lane] + fusbeta[lane];
  float sv = z / (1.0f + expf(-z));
  s_s[slot][lane] = sv;
  __syncthreads();

  float o = fusb2[lane];
#pragma unroll
  for (int j = 0; j < DD; ++j)
    o = fmaf(s_s[slot][j], fusW2[j * DD + lane], o);
  out[idx] = hd + o;
}

extern "C" void kernel_launch(void* const* d_in, const int* in_sizes, int n_in,
                              void* d_out, int out_size, void* d_ws, size_t ws_size,
                              hipStream_t stream) {
  (void)in_sizes; (void)n_in; (void)out_size;
  const float* h        = (const float*)d_in[0];
  const float* Q        = (const float*)d_in[1];
  const int*   ei       = (const int*)d_in[2];
  const float* coeffs   = (const float*)d_in[3];
  const float* projW    = (const float*)d_in[4];
  const float* projb    = (const float*)d_in[5];
  const float* projg    = (const float*)d_in[6];
  const float* projbeta = (const float*)d_in[7];
  const float* fusW1    = (const float*)d_in[8];
  const float* fusb1    = (const float*)d_in[9];
  const float* fusg     = (const float*)d_in[10];
  const float* fusbeta  = (const float*)d_in[11];
  const float* fusW2    = (const float*)d_in[12];
  const float* fusb2    = (const float*)d_in[13];
  float* out = (float*)d_out;

  // workspace layout
  const size_t qi_bytes  = (size_t)EE * DD * DD;              // 204.8 MB
  const size_t qs_bytes  = (size_t)EE * DD * sizeof(__half);  // 12.8 MB
  const size_t col_bytes = (size_t)EE * sizeof(int);          // 0.8 MB
  const size_t idx_bytes = (size_t)(3 * NN + 2) * sizeof(int);
  const size_t f32_elems = 6u * (size_t)ND + NN + 64;
  const size_t need = qi_bytes + qs_bytes + col_bytes + idx_bytes +
                      f32_elems * sizeof(float) + 256;
  const bool fast = ws_size >= need;

  char*   Qi8 = (char*)d_ws;
  __half* Qs  = (__half*)((char*)d_ws + qi_bytes);
  int*  cols      = (int*)((char*)d_ws + qi_bytes + qs_bytes);
  int*  row_start = cols + EE;            // NN+1
  int*  cursor    = row_start + NN + 1;   // NN
  float* base = fast
      ? (float*)((char*)d_ws + ((qi_bytes + qs_bytes + col_bytes + idx_bytes + 255) & ~(size_t)255))
      : (float*)d_ws;
  float* uA   = base;             // [ND]
  float* uB   = uA + ND;          // [ND]
  float* T1   = uB + ND;          // [ND]
  float* T2   = T1 + ND;          // [ND]
  float* T3   = T2 + ND;          // [ND]
  float* T4   = T3 + ND;          // [ND]
  float* deg  = T4 + ND;          // [NN]
  float* scal = deg + NN;         // [64]
  int*   hist = (int*)(scal + 64);  // [NN] — zeroed together with deg/scal

  (void)hipMemsetAsync(deg, 0, (2 * NN + 64) * sizeof(float), stream);

  k_deg<<<(EE + 255) / 256, 256, 0, stream>>>(ei, deg, hist);
  k_genv<<<ND / 256, 256, 0, stream>>>(uA);

  if (fast) {
    k_scan<<<1, 1024, 0, stream>>>(hist, row_start, cursor);
    k_cvt<<<EE / 8, 256, 0, stream>>>(Q, ei, cursor, Qi8, Qs, cols);

    // power iteration, unnormalized: u_{k+1} = L u_k
    float* cur = uA;
    float* nxt = uB;
    for (int it = 0; it < 5; ++it) {
      k_gather<<<NN / 4, 256, 0, stream>>>(cur, nullptr, Qi8, Qs, cols,
                                           row_start, deg, scal, nxt, 0);
      float* t = cur; cur = nxt; nxt = t;
    }
    k_dots<<<DOT_BLOCKS, 256, 0, stream>>>(nxt, cur, scal);
    k_alpha<<<1, 1, 0, stream>>>(scal);

    // Chebyshev: T1 = alpha*L h - h ; T_next = 2*(alpha*L x - x) - xprev
    const float* xin[4]   = {h, T1, T2, T3};
    const float* prevs[4] = {nullptr, h, T1, T2};
    float* touts[4]       = {T1, T2, T3, T4};
    for (int k = 0; k < 4; ++k) {
      k_gather<<<NN / 4, 256, 0, stream>>>(xin[k], prevs[k], Qi8, Qs, cols,
                                           row_start, deg, scal, touts[k],
                                           k == 0 ? 1 : 2);
    }
  } else {
    // f32 atomic-scatter fallback
    float* cur = uA;
    float* nxt = uB;
    for (int it = 0; it < 5; ++it) {
      k_pre<<<ND / 256, 256, 0, stream>>>(cur, nullptr, deg, scal, nxt, 0);
      k_matvec<<<EE / 8, 256, 0, stream>>>(cur, Q, ei, nxt, scal, 0, 1.0f);
      float* t = cur; cur = nxt; nxt = t;
    }
    k_dots<<<DOT_BLOCKS, 256, 0, stream>>>(nxt, cur, scal);
    k_alpha<<<1, 1, 0, stream>>>(scal);
    const float* xin[4]   = {h, T1, T2, T3};
    const float* prevs[4] = {nullptr, h, T1, T2};
    float* touts[4]       = {T1, T2, T3, T4};
    for (int k = 0; k < 4; ++k) {
      k_pre<<<ND / 256, 256, 0, stream>>>(xin[k], prevs[k], deg, scal, touts[k],
                                          k == 0 ? 1 : 2);
      k_matvec<<<EE / 8, 256, 0, stream>>>(xin[k], Q, ei, touts[k], scal, 1,
                                           k == 0 ? 1.0f : 2.0f);
    }
  }

  k_fuse<<<NN / 8, 256, 0, stream>>>(h, T1, T2, T3, T4, coeffs,
                                     projW, projb, projg, projbeta,
                                     fusW1, fusb1, fusg, fusbeta,
                                     fusW2, fusb2, out);
}